// Round 15
// baseline (631.887 us; speedup 1.0000x reference)
//
#include <hip/hip_runtime.h>
#include <hip/hip_bf16.h>
#include <math.h>

// Problem constants
#define Bn   2
#define Sn   1800
#define Dn   128
#define Hn   8
#define DKn  16
#define DFFn 512
#define Ln   6
#define Vn   16
#define LATn 1024
#define BSn  3600        // B*S
#define SDn  230400      // S*D
#define NQT  57          // ceil(1800/32)
#define VTJ  1824        // padded j-dim of transposed V
#define MPAD 3712        // padded row count for bf16 activation buffers

// Q pre-scale: 1/sqrt(16) * log2(e)  -> softmax runs in exp2 domain
#define QSCALE 0.3606737602222409f

typedef __attribute__((ext_vector_type(8))) short short8;   // 8 bf16 = 4 VGPR
typedef __attribute__((ext_vector_type(16))) float f32x16;
typedef unsigned int u32;
typedef unsigned short u16;

// MFMA 32x32x16 C/D layout: row = (reg&3) + 8*(reg>>2) + 4*hi, col = lane&31
#define ROWMAP(r, hi) (((r) & 3) + 8 * ((r) >> 2) + 4 * (hi))
// V-column permutation so PV's B-fragment needs no cross-lane exchange
#define GPERM(sl) (((sl) & 3) + (((sl) & 4) << 1) + (((sl) & 8) >> 1) + ((sl) & 16))

// native hardware exp2 (v_exp_f32); exp2f() lowers to the slow OCML call.
#define EXP2(x) __builtin_amdgcn_exp2f(x)

__device__ inline u32 cvtpk_bf16(float a, float b) {
    u32 r;
    asm("v_cvt_pk_bf16_f32 %0, %1, %2" : "=v"(r) : "v"(a), "v"(b));
    return r;
}

__device__ inline u16 f2bf(float f) {
    union { float f; u32 u; } x; x.f = f;
    u32 r = (x.u + 0x7FFFu + ((x.u >> 16) & 1u)) >> 16;
    return (u16)r;
}

__device__ inline float bf2f(u16 v) {
    union { u32 u; float f; } x; x.u = ((u32)v) << 16;
    return x.f;
}

// cross-half (lane <-> lane+32) combine. Proven primitive (rounds 2-4, 8-10, 14).
__device__ inline float xhalf_max(float t) {
    return fmaxf(t, __shfl_xor(t, 32));
}
__device__ inline float xhalf_sum(float t) {
    return t + __shfl_xor(t, 32);
}

// ---------------------------------------------------------------------------
// One-shot weight prep: 8 square mats transposed->bf16, ff_w1, ff_w2, Vt pad.
// Flat index space, grid 6176 x 256.
// ---------------------------------------------------------------------------
__global__ __launch_bounds__(256) void wprep_kernel(
    const float* __restrict__ s0, const float* __restrict__ s1,
    const float* __restrict__ s2, const float* __restrict__ s3,
    const float* __restrict__ s4, const float* __restrict__ s5,
    const float* __restrict__ s6, const float* __restrict__ s7,
    u16* __restrict__ d0, u16* __restrict__ d1, u16* __restrict__ d2,
    u16* __restrict__ d3, u16* __restrict__ d4, u16* __restrict__ d5,
    u16* __restrict__ d6, u16* __restrict__ d7,
    const float* __restrict__ f1s, u16* __restrict__ f1d,
    const float* __restrict__ f2s, u16* __restrict__ f2d,
    u16* __restrict__ Vt)
{
    const int id = blockIdx.x * 256 + threadIdx.x;
    if (id < 786432) {
        // 8 square mats [6][128][128]: dst[l][n][k] = src[l][k][n]
        const int z = id / 98304, rem = id % 98304;
        const float* src = (z == 0) ? s0 : (z == 1) ? s1 : (z == 2) ? s2 : (z == 3) ? s3
                         : (z == 4) ? s4 : (z == 5) ? s5 : (z == 6) ? s6 : s7;
        u16* dst = (z == 0) ? d0 : (z == 1) ? d1 : (z == 2) ? d2 : (z == 3) ? d3
                 : (z == 4) ? d4 : (z == 5) ? d5 : (z == 6) ? d6 : d7;
        const int l = rem >> 14, r2 = rem & 16383;
        const int n = r2 >> 7, k = r2 & 127;
        dst[rem] = f2bf(src[l * 16384 + k * 128 + n]);
    } else if (id < 786432 + 393216) {
        // ff_w1 [6][128][512] -> [6][512][128]
        const int rem = id - 786432;
        const int l = rem >> 16, r2 = rem & 65535;
        const int n = r2 >> 7, k = r2 & 127;
        f1d[rem] = f2bf(f1s[(size_t)l * 65536 + k * 512 + n]);
    } else if (id < 786432 + 786432) {
        // ff_w2 [6][512][128] -> [6][128][512]
        const int rem = id - 786432 - 393216;
        const int l = rem >> 16, r2 = rem & 65535;
        const int n = r2 >> 9, k = r2 & 511;
        f2d[rem] = f2bf(f2s[(size_t)l * 65536 + k * 128 + n]);
    } else {
        const int rem = id - 1572864;
        if (rem < 8192) {
            const int row = rem >> 5, pos = rem & 31;
            Vt[(size_t)row * VTJ + 1792 + pos] = 0;
        }
    }
}

// ---------------------------------------------------------------------------
// h = relu(latent @ lp_w1 + lp_b1)   [2, 256]
// ---------------------------------------------------------------------------
__global__ __launch_bounds__(256) void lat_h_kernel(
    const float* __restrict__ latent, const float* __restrict__ w1,
    const float* __restrict__ b1, float* __restrict__ h)
{
    __shared__ float ls[LATn];
    const int b = blockIdx.x;
    const int t = threadIdx.x;
    for (int k = t; k < LATn; k += 256) ls[k] = latent[b * LATn + k];
    __syncthreads();
    float acc = 0.f;
    #pragma unroll 8
    for (int k = 0; k < LATn; ++k) acc = fmaf(ls[k], w1[(size_t)k * 256 + t], acc);
    h[b * 256 + t] = fmaxf(acc + b1[t], 0.f);
}

// ---------------------------------------------------------------------------
// dec = h @ lp_w2 + lp_b2 + pos_encoding ; writes fp32 x and bf16 xb, encb
// ---------------------------------------------------------------------------
__global__ __launch_bounds__(256) void dec_kernel(
    const float* __restrict__ h, const float* __restrict__ w2,
    const float* __restrict__ b2, float* __restrict__ x,
    u16* __restrict__ xb, u16* __restrict__ encb)
{
    __shared__ float hs[512];
    const int t = threadIdx.x;
    hs[t] = h[t];
    hs[256 + t] = h[256 + t];
    __syncthreads();
    const int j = blockIdx.x * 256 + t;
    float a0 = 0.f, a1 = 0.f;
    #pragma unroll 8
    for (int k = 0; k < 256; ++k) {
        float w = w2[(size_t)k * SDn + j];
        a0 = fmaf(hs[k], w, a0);
        a1 = fmaf(hs[256 + k], w, a1);
    }
    const int s = j >> 7, d = j & 127;
    const int i2 = d >> 1;
    const float freq = __expf(-(float)(2 * i2) * (9.210340371976184f / 128.f));
    const float ang = (float)s * freq;
    const float pe = (d & 1) ? cosf(ang) : sinf(ang);
    const float bias = b2[j] + pe;
    const float v0 = a0 + bias;
    const float v1 = a1 + bias;
    x[j] = v0;
    x[SDn + j] = v1;
    xb[j] = f2bf(v0);    xb[SDn + j] = f2bf(v1);
    encb[j] = f2bf(v0);  encb[SDn + j] = f2bf(v1);
}

// ---------------------------------------------------------------------------
// QKV projection from a global bf16 activation (layer-0 self-attn only).
// ---------------------------------------------------------------------------
__global__ __launch_bounds__(256) void mm_qkv_kernel(
    const u16* __restrict__ Aq, const u16* __restrict__ Akv,
    const u16* __restrict__ Wq, const u16* __restrict__ Wk, const u16* __restrict__ Wv,
    const float* __restrict__ bq, const float* __restrict__ bk, const float* __restrict__ bv,
    u16* __restrict__ Qb, u16* __restrict__ Kb, u16* __restrict__ Vt)
{
    const int z = blockIdx.z;
    const u16* A = (z == 0) ? Aq : Akv;
    const u16* W = (z == 0) ? Wq : (z == 1) ? Wk : Wv;
    const float* Bi = (z == 0) ? bq : (z == 1) ? bk : bv;

    const int w = threadIdx.x >> 6;
    const int lane = threadIdx.x & 63;
    const int ql = lane & 31, hi = lane >> 5;
    const int m0 = blockIdx.x * 64 + (w & 1) * 32;
    const int nh = (w >> 1) * 64;

    f32x16 acc0 = (f32x16)0.0f, acc1 = (f32x16)0.0f;
    const size_t arow = (size_t)(m0 + ql) * 128;

    #pragma unroll
    for (int kk = 0; kk < 8; ++kk) {
        const short8 a = *(const short8*)(A + arow + kk * 16 + 8 * hi);
        const short8 b0 = *(const short8*)(W + (size_t)(nh + ql) * 128 + kk * 16 + 8 * hi);
        const short8 b1 = *(const short8*)(W + (size_t)(nh + 32 + ql) * 128 + kk * 16 + 8 * hi);
        acc0 = __builtin_amdgcn_mfma_f32_32x32x16_bf16(a, b0, acc0, 0, 0, 0);
        acc1 = __builtin_amdgcn_mfma_f32_32x32x16_bf16(a, b1, acc1, 0, 0, 0);
    }

    #pragma unroll
    for (int j = 0; j < 2; ++j) {
        const int n = nh + j * 32 + ql;
        const float bv_ = Bi[n];
        const int h = n >> 4, d = n & 15;
        #pragma unroll
        for (int r = 0; r < 16; ++r) {
            const int m = m0 + ROWMAP(r, hi);
            if (m >= BSn) continue;
            float v = (j ? acc1[r] : acc0[r]) + bv_;
            const int bq_ = (m >= Sn) ? 1 : 0;
            const int s = m - bq_ * Sn;
            const int bh = bq_ * 8 + h;
            if (z == 0) {
                Qb[((size_t)bh * Sn + s) * 16 + d] = f2bf(v * QSCALE);
            } else if (z == 1) {
                Kb[((size_t)bh * Sn + s) * 16 + d] = f2bf(v);
            } else {
                const int jt = s >> 5, sl = s & 31;
                Vt[((size_t)bh * 16 + d) * VTJ + jt * 32 + GPERM(sl)] = f2bf(v);
            }
        }
    }
}

// ---------------------------------------------------------------------------
// LN stats helper (256 threads, 32 rows x 128 cols in ls)
// ---------------------------------------------------------------------------
__device__ inline void ln_stats(const float* ls, float* mus, float* invs, int t)
{
    const int row = t >> 3, q = t & 7;
    float s1 = 0.f, s2 = 0.f;
    const float* lr = &ls[row * 132 + q * 16];
    #pragma unroll
    for (int c = 0; c < 16; c += 4) {
        const float4 v = *(const float4*)&lr[c];
        s1 += v.x + v.y + v.z + v.w;
        s2 += v.x * v.x + v.y * v.y + v.z * v.z + v.w * v.w;
    }
    s1 += __shfl_xor(s1, 1); s2 += __shfl_xor(s2, 1);
    s1 += __shfl_xor(s1, 2); s2 += __shfl_xor(s2, 2);
    s1 += __shfl_xor(s1, 4); s2 += __shfl_xor(s2, 4);
    const float mu = s1 * (1.f / 128.f);
    const float var = s2 * (1.f / 128.f) - mu * mu;
    if (q == 0) { mus[row] = mu; invs[row] = rsqrtf(var + 1e-5f); }
}

// ---------------------------------------------------------------------------
// K2: O-proj(self) + residual + LN1 -> x (fp32) & LDS y (bf16);
// then cross-attn QKV: Q = y@Wq, K/V = encb@Wk/Wv -> Qb, Kb, Vt.
// ---------------------------------------------------------------------------
__global__ __launch_bounds__(256) void fuse_oln_qkv_kernel(
    const u16* __restrict__ A, const u16* __restrict__ Wo,
    const float* __restrict__ bo,
    const float* __restrict__ g, const float* __restrict__ bb,
    float* __restrict__ X, const u16* __restrict__ Enc,
    const u16* __restrict__ Wq, const u16* __restrict__ Wk, const u16* __restrict__ Wv,
    const float* __restrict__ bq, const float* __restrict__ bk, const float* __restrict__ bv,
    u16* __restrict__ Qb, u16* __restrict__ Kb, u16* __restrict__ Vt)
{
    __shared__ float ls[32 * 132];
    __shared__ float mus[32], invs[32];
    __shared__ alignas(16) u16 ybuf[32][136];

    const int t = threadIdx.x;
    const int w = t >> 6, lane = t & 63;
    const int ql = lane & 31, hi = lane >> 5;
    const int m0 = blockIdx.x * 32;

    {
        f32x16 acc = (f32x16)0.0f;
        const size_t arow = (size_t)(m0 + ql) * 128;
        const int nh = w * 32;
        #pragma unroll
        for (int kk = 0; kk < 8; ++kk) {
            const short8 a = *(const short8*)(A + arow + kk * 16 + 8 * hi);
            const short8 b0 = *(const short8*)(Wo + (size_t)(nh + ql) * 128 + kk * 16 + 8 * hi);
            acc = __builtin_amdgcn_mfma_f32_32x32x16_bf16(a, b0, acc, 0, 0, 0);
        }
        const int n = nh + ql;
        const float bv_ = bo[n];
        #pragma unroll
        for (int r = 0; r < 16; ++r) {
            const int row = ROWMAP(r, hi);
            const int gm = m0 + row;
            float v = acc[r] + bv_;
            if (gm < BSn) v += X[(size_t)gm * 128 + n];
            ls[row * 132 + n] = v;
        }
    }
    __syncthreads();
    ln_stats(ls, mus, invs, t);
    __syncthreads();
    #pragma unroll
    for (int it = 0; it < 4; ++it) {
        const int idx = it * 256 + t;
        const int row = idx >> 5, cg = (idx & 31) * 4;
        const int gm = m0 + row;
        const float4 v = *(const float4*)&ls[row * 132 + cg];
        const float mu = mus[row], inv = invs[row];
        const float4 gv = *(const float4*)&g[cg];
        const float4 bv2 = *(const float4*)&bb[cg];
        float4 y;
        y.x = (v.x - mu) * inv * gv.x + bv2.x;
        y.y = (v.y - mu) * inv * gv.y + bv2.y;
        y.z = (v.z - mu) * inv * gv.z + bv2.z;
        y.w = (v.w - mu) * inv * gv.w + bv2.w;
        if (gm < BSn) *(float4*)&X[(size_t)gm * 128 + cg] = y;
        uint2 u;
        u.x = cvtpk_bf16(y.x, y.y);
        u.y = cvtpk_bf16(y.z, y.w);
        *(uint2*)&ybuf[row][cg] = u;
    }
    __syncthreads();

    #pragma unroll
    for (int z = 0; z < 3; ++z) {
        const u16* W = (z == 0) ? Wq : (z == 1) ? Wk : Wv;
        const float* Bi = (z == 0) ? bq : (z == 1) ? bk : bv;
        f32x16 acc = (f32x16)0.0f;
        const int nh = w * 32;
        #pragma unroll
        for (int kk = 0; kk < 8; ++kk) {
            short8 a;
            if (z == 0) a = *(const short8*)&ybuf[ql][kk * 16 + 8 * hi];
            else        a = *(const short8*)(Enc + (size_t)(m0 + ql) * 128 + kk * 16 + 8 * hi);
            const short8 b0 = *(const short8*)(W + (size_t)(nh + ql) * 128 + kk * 16 + 8 * hi);
            acc = __builtin_amdgcn_mfma_f32_32x32x16_bf16(a, b0, acc, 0, 0, 0);
        }
        const int n = nh + ql;
        const float bv_ = Bi[n];
        const int h = n >> 4, d = n & 15;
        #pragma unroll
        for (int r = 0; r < 16; ++r) {
            const int m = m0 + ROWMAP(r, hi);
            if (m >= BSn) continue;
            float v = acc[r] + bv_;
            const int bq_ = (m >= Sn) ? 1 : 0;
            const int s = m - bq_ * Sn;
            const int bh = bq_ * 8 + h;
            if (z == 0)      Qb[((size_t)bh * Sn + s) * 16 + d] = f2bf(v * QSCALE);
            else if (z == 1) Kb[((size_t)bh * Sn + s) * 16 + d] = f2bf(v);
            else             Vt[((size_t)bh * 16 + d) * VTJ + (s >> 5) * 32 + GPERM(s & 31)] = f2bf(v);
        }
    }
}

// ---------------------------------------------------------------------------
// K4: O-proj(cross) + residual + LN2 + FF1 + FF2 + residual + LN3 -> x;
// then (if WITH_QKV) next layer's self-attn QKV.
// ---------------------------------------------------------------------------
template <int WITH_QKV>
__global__ __launch_bounds__(256) void fuse_ffn_kernel(
    const u16* __restrict__ A, const u16* __restrict__ Wo,
    const float* __restrict__ bo,
    const float* __restrict__ g2, const float* __restrict__ b2ln,
    const u16* __restrict__ W1, const float* __restrict__ b1,
    const u16* __restrict__ W2, const float* __restrict__ b2f,
    const float* __restrict__ g3, const float* __restrict__ b3ln,
    float* __restrict__ X,
    const u16* __restrict__ Wq, const u16* __restrict__ Wk, const u16* __restrict__ Wv,
    const float* __restrict__ bq, const float* __restrict__ bk, const float* __restrict__ bv,
    u16* __restrict__ Qb, u16* __restrict__ Kb, u16* __restrict__ Vt)
{
    __shared__ float ls[32 * 132];
    __shared__ float mus[32], invs[32];
    __shared__ alignas(16) u16 ybuf[32][136];
    __shared__ alignas(16) u16 hbuf[32][536];

    const int t = threadIdx.x;
    const int w = t >> 6, lane = t & 63;
    const int ql = lane & 31, hi = lane >> 5;
    const int m0 = blockIdx.x * 32;

    {
        f32x16 acc = (f32x16)0.0f;
        const size_t arow = (size_t)(m0 + ql) * 128;
        const int nh = w * 32;
        #pragma unroll
        for (int kk = 0; kk < 8; ++kk) {
            const short8 a = *(const short8*)(A + arow + kk * 16 + 8 * hi);
            const short8 b0 = *(const short8*)(Wo + (size_t)(nh + ql) * 128 + kk * 16 + 8 * hi);
            acc = __builtin_amdgcn_mfma_f32_32x32x16_bf16(a, b0, acc, 0, 0, 0);
        }
        const int n = nh + ql;
        const float bv_ = bo[n];
        #pragma unroll
        for (int r = 0; r < 16; ++r) {
            const int row = ROWMAP(r, hi);
            const int gm = m0 + row;
            float v = acc[r] + bv_;
            if (gm < BSn) v += X[(size_t)gm * 128 + n];
            ls[row * 132 + n] = v;
        }
    }
    __syncthreads();
    ln_stats(ls, mus, invs, t);
    __syncthreads();
    #pragma unroll
    for (int it = 0; it < 4; ++it) {
        const int idx = it * 256 + t;
        const int row = idx >> 5, cg = (idx & 31) * 4;
        const float4 v = *(const float4*)&ls[row * 132 + cg];
        const float mu = mus[row], inv = invs[row];
        const float4 gv = *(const float4*)&g2[cg];
        const float4 bv2 = *(const float4*)&b2ln[cg];
        float4 y;
        y.x = (v.x - mu) * inv * gv.x + bv2.x;
        y.y = (v.y - mu) * inv * gv.y + bv2.y;
        y.z = (v.z - mu) * inv * gv.z + bv2.z;
        y.w = (v.w - mu) * inv * gv.w + bv2.w;
        *(float4*)&ls[row * 132 + cg] = y;
        uint2 u;
        u.x = cvtpk_bf16(y.x, y.y);
        u.y = cvtpk_bf16(y.z, y.w);
        *(uint2*)&ybuf[row][cg] = u;
    }
    __syncthreads();

    #pragma unroll
    for (int nt = 0; nt < 4; ++nt) {
        const int n0 = w * 128 + nt * 32;
        f32x16 acc = (f32x16)0.0f;
        #pragma unroll
        for (int kk = 0; kk < 8; ++kk) {
            const short8 a = *(const short8*)&ybuf[ql][kk * 16 + 8 * hi];
            const short8 b0 = *(const short8*)(W1 + (size_t)(n0 + ql) * 128 + kk * 16 + 8 * hi);
            acc = __builtin_amdgcn_mfma_f32_32x32x16_bf16(a, b0, acc, 0, 0, 0);
        }
        const int n = n0 + ql;
        const float bv_ = b1[n];
        #pragma unroll
        for (int r = 0; r < 16; ++r) {
            const int row = ROWMAP(r, hi);
            hbuf[row][n] = f2bf(fmaxf(acc[r] + bv_, 0.f));
        }
    }
    __syncthreads();

    {
        f32x16 acc = (f32x16)0.0f;
        const int nh = w * 32;
        #pragma unroll
        for (int kk = 0; kk < 32; ++kk) {
            const short8 a = *(const short8*)&hbuf[ql][kk * 16 + 8 * hi];
            const short8 b0 = *(const short8*)(W2 + (size_t)(nh + ql) * 512 + kk * 16 + 8 * hi);
            acc = __builtin_amdgcn_mfma_f32_32x32x16_bf16(a, b0, acc, 0, 0, 0);
        }
        const int n = nh + ql;
        const float bv_ = b2f[n];
        #pragma unroll
        for (int r = 0; r < 16; ++r) {
            const int row = ROWMAP(r, hi);
            ls[row * 132 + n] = acc[r] + bv_ + ls[row * 132 + n];
        }
    }
    __syncthreads();
    ln_stats(ls, mus, invs, t);
    __syncthreads();
    #pragma unroll
    for (int it = 0; it < 4; ++it) {
        const int idx = it * 256 + t;
        const int row = idx >> 5, cg = (idx & 31) * 4;
        const int gm = m0 + row;
        const float4 v = *(const float4*)&ls[row * 132 + cg];
        const float mu = mus[row], inv = invs[row];
        const float4 gv = *(const float4*)&g3[cg];
        const float4 bv2 = *(const float4*)&b3ln[cg];
        float4 y;
        y.x = (v.x - mu) * inv * gv.x + bv2.x;
        y.y = (v.y - mu) * inv * gv.y + bv2.y;
        y.z = (v.z - mu) * inv * gv.z + bv2.z;
        y.w = (v.w - mu) * inv * gv.w + bv2.w;
        if (gm < BSn) *(float4*)&X[(size_t)gm * 128 + cg] = y;
        uint2 u;
        u.x = cvtpk_bf16(y.x, y.y);
        u.y = cvtpk_bf16(y.z, y.w);
        *(uint2*)&ybuf[row][cg] = u;
    }

    if (WITH_QKV) {
        __syncthreads();
        #pragma unroll
        for (int z = 0; z < 3; ++z) {
            const u16* W = (z == 0) ? Wq : (z == 1) ? Wk : Wv;
            const float* Bi = (z == 0) ? bq : (z == 1) ? bk : bv;
            f32x16 acc = (f32x16)0.0f;
            const int nh = w * 32;
            #pragma unroll
            for (int kk = 0; kk < 8; ++kk) {
                const short8 a = *(const short8*)&ybuf[ql][kk * 16 + 8 * hi];
                const short8 b0 = *(const short8*)(W + (size_t)(nh + ql) * 128 + kk * 16 + 8 * hi);
                acc = __builtin_amdgcn_mfma_f32_32x32x16_bf16(a, b0, acc, 0, 0, 0);
            }
            const int n = nh + ql;
            const float bv_ = Bi[n];
            const int h = n >> 4, d = n & 15;
            #pragma unroll
            for (int r = 0; r < 16; ++r) {
                const int m = m0 + ROWMAP(r, hi);
                if (m >= BSn) continue;
                float v = acc[r] + bv_;
                const int bq_ = (m >= Sn) ? 1 : 0;
                const int s = m - bq_ * Sn;
                const int bh = bq_ * 8 + h;
                if (z == 0)      Qb[((size_t)bh * Sn + s) * 16 + d] = f2bf(v * QSCALE);
                else if (z == 1) Kb[((size_t)bh * Sn + s) * 16 + d] = f2bf(v);
                else             Vt[((size_t)bh * 16 + d) * VTJ + (s >> 5) * 32 + GPERM(s & 31)] = f2bf(v);
            }
        }
    }
}

// ---------------------------------------------------------------------------
// MFMA flash attention, 4-way split-KV, PAIR processing (KVBLK=64):
// each wave handles tile pairs (jt, jt+1) with one shared max/rescale --
// algebraically identical online softmax, half the serial iterations.
// Isolated re-test on the proven (slack) workspace layout.
// ---------------------------------------------------------------------------
template <int MASK>
__global__ __launch_bounds__(256) void flash_mfma(
    const u16* __restrict__ Qb, const u16* __restrict__ Kb,
    const u16* __restrict__ Vt, u16* __restrict__ Ob)
{
    __shared__ float mrg[4][64][10];

    const int wid = threadIdx.x >> 6;
    const int lane = threadIdx.x & 63;
    const int bh = blockIdx.y;
    const int b = bh >> 3, h = bh & 7;

    if (MASK && blockIdx.x == NQT) {
        const int d = threadIdx.x & 15, part = threadIdx.x >> 4;
        const u16* row = Vt + ((size_t)bh * 16 + d) * VTJ;
        float s = 0.f;
        for (int j = part; j < VTJ; j += 16) s += bf2f(row[j]);
        ((float*)mrg)[part * 16 + d] = s;
        __syncthreads();
        if (threadIdx.x < 16) {
            float tot = 0.f;
            #pragma unroll
            for (int p = 0; p < 16; ++p) tot += ((float*)mrg)[p * 16 + threadIdx.x];
            Ob[((size_t)(b * Sn + (Sn - 1))) * 128 + h * 16 + threadIdx.x] =
                f2bf(tot * (1.f / (float)Sn));
        }
        return;
    }

    const int ql = lane & 31, hi = lane >> 5;
    const int qt = blockIdx.x;
    const int qrow = qt * 32 + ql;
    const int qr = (qrow < Sn) ? qrow : (Sn - 1);
    const short8 qf = *(const short8*)(Qb + ((size_t)bh * Sn + qr) * 16 + 8 * hi);
    const u16* kbase = Kb + (size_t)bh * Sn * 16;
    const u16* vbase = Vt + ((size_t)bh * 16 + (ql & 15)) * VTJ;

    f32x16 acc = (f32x16)0.0f;
    float m = -INFINITY, lsum = 0.f;

    int jt = (MASK ? qt : 0) + 2 * wid;
    short8 kfA = (short8)0, kfB = (short8)0;
    short8 vaA = (short8)0, vbA = (short8)0, vaB = (short8)0, vbB = (short8)0;
    if (jt < NQT) {
        int ra = jt * 32 + ql; if (ra >= Sn) ra = Sn - 1;
        const int jb = (jt + 1 < NQT) ? jt + 1 : jt;
        int rb = jb * 32 + ql; if (rb >= Sn) rb = Sn - 1;
        kfA = *(const short8*)(kbase + (size_t)ra * 16 + 8 * hi);
        kfB = *(const short8*)(kbase + (size_t)rb * 16 + 8 * hi);
        vaA = *(const short8*)(vbase + jt * 32 + 8 * hi);
        vbA = *(const short8*)(vbase + jt * 32 + 16 + 8 * hi);
        vaB = *(const short8*)(vbase + jb * 32 + 8 * hi);
        vbB = *(const short8*)(vbase + jb * 32 + 16 + 8 * hi);
    }

    for (; jt < NQT; jt += 8) {
        short8 nkA = kfA, nkB = kfB, nvA = vaA, nvbA = vbA, nvB = vaB, nvbB = vbB;
        if (jt + 8 < NQT) {
            const int na = jt + 8;
            const int nb = (na + 1 < NQT) ? na + 1 : na;
            int ra = na * 32 + ql; if (ra >= Sn) ra = Sn - 1;
            int rb = nb * 32 + ql; if (rb >= Sn) rb = Sn - 1;
            nkA  = *(const short8*)(kbase + (size_t)ra * 16 + 8 * hi);
            nkB  = *(const short8*)(kbase + (size_t)rb * 16 + 8 * hi);
            nvA  = *(const short8*)(vbase + na * 32 + 8 * hi);
            nvbA = *(const short8*)(vbase + na * 32 + 16 + 8 * hi);
            nvB  = *(const short8*)(vbase + nb * 32 + 8 * hi);
            nvbB = *(const short8*)(vbase + nb * 32 + 16 + 8 * hi);
        }

        const f32x16 scA = __builtin_amdgcn_mfma_f32_32x32x16_bf16(kfA, qf, (f32x16)0.0f, 0, 0, 0);
        const f32x16 scB = __builtin_amdgcn_mfma_f32_32x32x16_bf16(kfB, qf, (f32x16)0.0f, 0, 0, 0);

        float sv[32];
        #pragma unroll
        for (int r = 0; r < 16; ++r) { sv[r] = scA[r]; sv[16 + r] = scB[r]; }

        if (MASK && jt == qt) {
            #pragma unroll
            for (int r = 0; r < 16; ++r)
                if (!(ROWMAP(r, hi) > ql)) sv[r] = -1e9f;
        }
        const int jtB = jt + 1;
        if (jtB >= NQT) {
            #pragma unroll
            for (int r = 0; r < 16; ++r) sv[16 + r] = -1e30f;
        }
        if (jt == NQT - 1) {
            #pragma unroll
            for (int r = 0; r < 16; ++r)
                if (1792 + ROWMAP(r, hi) >= Sn) sv[r] = -1e30f;
        }
        if (jtB == NQT - 1) {
            #pragma unroll
            for (int r = 0; r < 16; ++r)
                if (1792 + ROWMAP(r, hi) >= Sn) sv[16 + r] = -1e30f;
        }

        // pairwise max then depth-3 tree over 16
        float mx[16];
        #pragma unroll
        for (int r = 0; r < 16; ++r) mx[r] = fmaxf(sv[r], sv[16 + r]);
        const float a0 = fmaxf(fmaxf(mx[0], mx[1]), mx[2]);
        const float a1 = fmaxf(fmaxf(mx[3], mx[4]), mx[5]);
        const float a2 = fmaxf(fmaxf(mx[6], mx[7]), mx[8]);
        const float a3 = fmaxf(fmaxf(mx[9], mx[10]), mx[11]);
        const float a4 = fmaxf(fmaxf(mx[12], mx[13]), mx[14]);
        const float b0m = fmaxf(fmaxf(a0, a1), a2);
        const float b1m = fmaxf(fmaxf(a3, a4), mx[15]);
        const float tmax = xhalf_max(fmaxf(b0m, b1m));

        const float mnew = fmaxf(m, tmax);
        const float corr = EXP2(m - mnew);
        m = mnew;
        lsum *= corr;
        #pragma unroll
        for (int r = 0; r < 16; ++r) acc[r] *= corr;

        float ps = 0.f;
        #pragma unroll
        for (int r = 0; r < 32; ++r) { sv[r] = EXP2(sv[r] - m); ps += sv[r]; }
        lsum += ps;

        union { u32 u[4]; short8 s; } A0c, A1c, B0c, B1c;
        A0c.u[0] = cvtpk_bf16(sv[0],  sv[1]);  A0c.u[1] = cvtpk_bf16(sv[2],  sv[3]);
        A0c.u[2] = cvtpk_bf16(sv[4],  sv[5]);  A0c.u[3] = cvtpk_bf16(sv[6],  sv[7]);
        A1c.u[0] = cvtpk_bf16(sv[8],  sv[9]);  A1c.u[1] = cvtpk_bf16(sv[10], sv[11]);
        A1c.u[2] = cvtpk_bf16(sv[12], sv[13]); A1c.u[3] = cvtpk_bf16(sv[14], sv[15]);
        B0c.u[0] = cvtpk_bf16(sv[16], sv[17]); B0c.u[1] = cvtpk_bf16(sv[18], sv[19]);
        B0c.u[2] = cvtpk_bf16(sv[20], sv[21]); B0c.u[3] = cvtpk_bf16(sv[22], sv[23]);
        B1c.u[0] = cvtpk_bf16(sv[24], sv[25]); B1c.u[1] = cvtpk_bf16(sv[26], sv[27]);
        B1c.u[2] = cvtpk_bf16(sv[28], sv[29]); B1c.u[3] = cvtpk_bf16(sv[30], sv[31]);

        acc = __builtin_amdgcn_mfma_f32_32x32x16_bf16(vaA, A0c.s, acc, 0, 0, 0);
        acc = __builtin_amdgcn_mfma_f32_32x32x16_bf16(vbA, A1c.s, acc, 0, 0, 0);
        acc = __builtin_amdgcn_mfma_f32_32x32x16_bf16(vaB, B0c.s, acc, 0, 0, 0);
        acc = __builtin_amdgcn_mfma_f32_32x32x16_bf16(vbB, B1c.s, acc, 0, 0, 0);

        kfA = nkA; kfB = nkB; vaA = nvA; vbA = nvbA; vaB = nvB; vbB = nvbB;
    }

    mrg[wid][lane][0] = m;
    mrg[wid][lane][1] = lsum;
    #pragma unroll
    for (int r = 0; r < 8; ++r) mrg[wid][lane][2 + r] = acc[r];
    __syncthreads();

    if (wid == 0) {
        float mstar = mrg[0][lane][0];
        #pragma unroll
        for (int w2 = 1; w2 < 4; ++w2) mstar = fmaxf(mstar, mrg[w2][lane][0]);
        float lt = 0.f;
        float accf[8] = {};
        #pragma unroll
        for (int w2 = 0; w2 < 4; ++w2) {
            const float sc2 = EXP2(mrg[w2][lane][0] - mstar);
            lt += mrg[w2][lane][1] * sc2;
            #pragma unroll
            for (int r = 0; r < 8; ++r) accf[r] = fmaf(mrg[w2][lane][2 + r], sc2, accf[r]);
        }
        const float ltot = xhalf_sum(lt);
        const float inv = 1.f / ltot;
        if (qrow < Sn && !(MASK && qrow == Sn - 1)) {
            u16* op = Ob + ((size_t)(b * Sn + qrow)) * 128 + h * 16;
            uint2 u0, u1;
            u0.x = cvtpk_bf16(accf[0] * inv, accf[1] * inv);
            u0.y = cvtpk_bf16(accf[2] * inv, accf[3] * inv);
            u1.x = cvtpk_bf16(accf[4] * inv, accf[5] * inv);
            u1.y = cvtpk_bf16(accf[6] * inv, accf[7] * inv);
            *(uint2*)(op + 4 * hi) = u0;
            *(uint2*)(op + 8 + 4 * hi) = u1;
        }
    }
}

// ---------------------------------------------------------------------------
// logits = x @ out_w + out_b   [3600,128]@[128,16]  (fp32)
// ---------------------------------------------------------------------------
__global__ __launch_bounds__(256) void out_kernel(
    const float* __restrict__ X, const float* __restrict__ W,
    const float* __restrict__ bb, float* __restrict__ out)
{
    const int t = threadIdx.x;
    const int n = t & 15;
    const int r = blockIdx.x * 16 + (t >> 4);
    if (r >= BSn) return;
    float acc = 0.f;
    #pragma unroll 8
    for (int k = 0; k < 128; ++k)
        acc = fmaf(X[(size_t)r * 128 + k], W[k * 16 + n], acc);
    out[(size_t)r * 16 + n] = acc + bb[n];
}

// ---------------------------------------------------------------------------
extern "C" void kernel_launch(void* const* d_in, const int* in_sizes, int n_in,
                              void* d_out, int out_size, void* d_ws, size_t ws_size,
                              hipStream_t stream)
{
    const float* latent = (const float*)d_in[0];
    const float* lp_w1  = (const float*)d_in[1];
    const float* lp_b1  = (const float*)d_in[2];
    const float* lp_w2  = (const float*)d_in[3];
    const float* lp_b2  = (const float*)d_in[4];
    const float* out_w  = (const float*)d_in[5];
    const float* out_b  = (const float*)d_in[6];
    const float* sa_wq = (const float*)d_in[7];  const float* sa_bq = (const float*)d_in[8];
    const float* sa_wk = (const float*)d_in[9];  const float* sa_bk = (const float*)d_in[10];
    const float* sa_wv = (const float*)d_in[11]; const float* sa_bv = (const float*)d_in[12];
    const float* sa_wo = (const float*)d_in[13]; const float* sa_bo = (const float*)d_in[14];
    const float* ca_wq = (const float*)d_in[15]; const float* ca_bq = (const float*)d_in[16];
    const float* ca_wk = (const float*)d_in[17]; const float* ca_bk = (const float*)d_in[18];
    const float* ca_wv = (const float*)d_in[19]; const float* ca_bv = (const float*)d_in[20];
    const float* ca_wo = (const float*)d_in[21]; const float* ca_bo = (const float*)d_in[22];
    const float* ff_w1 = (const float*)d_in[23]; const float* ff_b1 = (const float*)d_in[24];
    const float* ff_w2 = (const float*)d_in[25]; const float* ff_b2 = (const float*)d_in[26];
    const float* ln1g = (const float*)d_in[27]; const float* ln1b = (const float*)d_in[28];
    const float* ln2g = (const float*)d_in[29]; const float* ln2b = (const float*)d_in[30];
    const float* ln3g = (const float*)d_in[31]; const float* ln3b = (const float*)d_in[32];

    float* ws = (float*)d_ws;
    float* x    = ws;                         // 460800 f
    float* hlat = ws + 460800;                // 512 f
    u16* xb   = (u16*)(ws + 461312);          // MPAD*128 us = 237568 f (layer-0 only)
    u16* encb = (u16*)(ws + 698880);          // 237568 f
    u16* ob   = (u16*)(ws + 936448);          // 237568 f
    u16* Qb   = (u16*)(ws + 2124288);         // 230400 f
    u16* Kb   = (u16*)(ws + 2354688);         // 230400 f
    u16* Vt   = (u16*)(ws + 2585088);         // 16*16*1824 us = 233472 f
    u16* wt_saq = (u16*)(ws + 2818560);       // 8 square mats, 49152 f each
    u16* wt_sak = wt_saq + 6 * 16384;
    u16* wt_sav = wt_sak + 6 * 16384;
    u16* wt_sao = wt_sav + 6 * 16384;
    u16* wt_caq = wt_sao + 6 * 16384;
    u16* wt_cak = wt_caq + 6 * 16384;
    u16* wt_cav = wt_cak + 6 * 16384;
    u16* wt_cao = wt_cav + 6 * 16384;
    u16* wt1  = (u16*)(ws + 3211776);         // [6][512][128] us = 196608 f
    u16* wt2  = (u16*)(ws + 3408384);         // [6][128][512] us = 196608 f

    wprep_kernel<<<dim3(6176), dim3(256), 0, stream>>>(
        sa_wq, sa_wk, sa_wv, sa_wo, ca_wq, ca_wk, ca_wv, ca_wo,
        wt_saq, wt_sak, wt_sav, wt_sao, wt_caq, wt_cak, wt_cav, wt_cao,
        ff_w1, wt1, ff_w2, wt2, Vt);

    lat_h_kernel<<<dim3(2), dim3(256), 0, stream>>>(latent, lp_w1, lp_b1, hlat);
    dec_kernel<<<dim3(900), dim3(256), 0, stream>>>(hlat, lp_w2, lp_b2, x, xb, encb);

    const dim3 thr(256);
    const dim3 gFm(NQT + 1, 16), gFc(NQT, 16), gFuse(113);

    // layer-0 self-attn QKV from xb
    mm_qkv_kernel<<<dim3(57, 1, 3), thr, 0, stream>>>(
        xb, xb, wt_saq, wt_sak, wt_sav, sa_bq, sa_bk, sa_bv, Qb, Kb, Vt);

    for (int i = 0; i < Ln; ++i) {
        const size_t wOff = (size_t)i * 16384;
        const size_t bOff = (size_t)i * 128;
        const size_t fOff = (size_t)i * 65536;
        const size_t f1b  = (size_t)i * 512;
        const size_t wNxt = (size_t)(i + 1) * 16384;
        const size_t bNxt = (size_t)(i + 1) * 128;

        flash_mfma<1><<<gFm, thr, 0, stream>>>(Qb, Kb, Vt, ob);

        fuse_oln_qkv_kernel<<<gFuse, thr, 0, stream>>>(
            ob, wt_sao + wOff, sa_bo + bOff, ln1g + bOff, ln1b + bOff, x, encb,
            wt_caq + wOff, wt_cak + wOff, wt_cav + wOff,
            ca_bq + bOff, ca_bk + bOff, ca_bv + bOff, Qb, Kb, Vt);

        flash_mfma<0><<<gFc, thr, 0, stream>>>(Qb, Kb, Vt, ob);

        if (i < Ln - 1) {
            fuse_ffn_kernel<1><<<gFuse, thr, 0, stream>>>(
                ob, wt_cao + wOff, ca_bo + bOff, ln2g + bOff, ln2b + bOff,
                wt1 + fOff, ff_b1 + f1b, wt2 + fOff, ff_b2 + bOff,
                ln3g + bOff, ln3b + bOff, x,
                wt_saq + wNxt, wt_sak + wNxt, wt_sav + wNxt,
                sa_bq + bNxt, sa_bk + bNxt, sa_bv + bNxt, Qb, Kb, Vt);
        } else {
            fuse_ffn_kernel<0><<<gFuse, thr, 0, stream>>>(
                ob, wt_cao + wOff, ca_bo + bOff, ln2g + bOff, ln2b + bOff,
                wt1 + fOff, ff_b1 + f1b, wt2 + fOff, ff_b2 + bOff,
                ln3g + bOff, ln3b + bOff, x,
                wt_saq, wt_sak, wt_sav, sa_bq, sa_bk, sa_bv, Qb, Kb, Vt);
        }
    }

    out_kernel<<<dim3(225), dim3(256), 0, stream>>>(x, out_w, out_b, (float*)d_out);
}

// Round 16
// 591.121 us; speedup vs baseline: 1.0690x; 1.0690x over previous
//
#include <hip/hip_runtime.h>
#include <hip/hip_bf16.h>
#include <math.h>

// Problem constants
#define Bn   2
#define Sn   1800
#define Dn   128
#define Hn   8
#define DKn  16
#define DFFn 512
#define Ln   6
#define Vn   16
#define LATn 1024
#define BSn  3600        // B*S
#define SDn  230400      // S*D
#define NQT  57          // ceil(1800/32)
#define VTJ  1824        // padded j-dim of transposed V
#define MPAD 3712        // padded row count for bf16 activation buffers

// Q pre-scale: 1/sqrt(16) * log2(e)  -> softmax runs in exp2 domain
#define QSCALE 0.3606737602222409f

typedef __attribute__((ext_vector_type(8))) short short8;   // 8 bf16 = 4 VGPR
typedef __attribute__((ext_vector_type(16))) float f32x16;
typedef unsigned int u32;
typedef unsigned short u16;

// MFMA 32x32x16 C/D layout: row = (reg&3) + 8*(reg>>2) + 4*hi, col = lane&31
#define ROWMAP(r, hi) (((r) & 3) + 8 * ((r) >> 2) + 4 * (hi))
// V-column permutation so PV's B-fragment needs no cross-lane exchange
#define GPERM(sl) (((sl) & 3) + (((sl) & 4) << 1) + (((sl) & 8) >> 1) + ((sl) & 16))

// native hardware exp2 (v_exp_f32); exp2f() lowers to the slow OCML call.
#define EXP2(x) __builtin_amdgcn_exp2f(x)

__device__ inline u32 cvtpk_bf16(float a, float b) {
    u32 r;
    asm("v_cvt_pk_bf16_f32 %0, %1, %2" : "=v"(r) : "v"(a), "v"(b));
    return r;
}

__device__ inline u16 f2bf(float f) {
    union { float f; u32 u; } x; x.f = f;
    u32 r = (x.u + 0x7FFFu + ((x.u >> 16) & 1u)) >> 16;
    return (u16)r;
}

__device__ inline float bf2f(u16 v) {
    union { u32 u; float f; } x; x.u = ((u32)v) << 16;
    return x.f;
}

// cross-half (lane <-> lane+32) combine. Proven primitive (rounds 2-4, 8-10, 14-15).
__device__ inline float xhalf_max(float t) {
    return fmaxf(t, __shfl_xor(t, 32));
}
__device__ inline float xhalf_sum(float t) {
    return t + __shfl_xor(t, 32);
}

// ---------------------------------------------------------------------------
// One-shot weight prep: 8 square mats transposed->bf16, ff_w1, ff_w2, Vt pad.
// Flat index space, grid 6176 x 256.
// ---------------------------------------------------------------------------
__global__ __launch_bounds__(256) void wprep_kernel(
    const float* __restrict__ s0, const float* __restrict__ s1,
    const float* __restrict__ s2, const float* __restrict__ s3,
    const float* __restrict__ s4, const float* __restrict__ s5,
    const float* __restrict__ s6, const float* __restrict__ s7,
    u16* __restrict__ d0, u16* __restrict__ d1, u16* __restrict__ d2,
    u16* __restrict__ d3, u16* __restrict__ d4, u16* __restrict__ d5,
    u16* __restrict__ d6, u16* __restrict__ d7,
    const float* __restrict__ f1s, u16* __restrict__ f1d,
    const float* __restrict__ f2s, u16* __restrict__ f2d,
    u16* __restrict__ Vt)
{
    const int id = blockIdx.x * 256 + threadIdx.x;
    if (id < 786432) {
        // 8 square mats [6][128][128]: dst[l][n][k] = src[l][k][n]
        const int z = id / 98304, rem = id % 98304;
        const float* src = (z == 0) ? s0 : (z == 1) ? s1 : (z == 2) ? s2 : (z == 3) ? s3
                         : (z == 4) ? s4 : (z == 5) ? s5 : (z == 6) ? s6 : s7;
        u16* dst = (z == 0) ? d0 : (z == 1) ? d1 : (z == 2) ? d2 : (z == 3) ? d3
                 : (z == 4) ? d4 : (z == 5) ? d5 : (z == 6) ? d6 : d7;
        const int l = rem >> 14, r2 = rem & 16383;
        const int n = r2 >> 7, k = r2 & 127;
        dst[rem] = f2bf(src[l * 16384 + k * 128 + n]);
    } else if (id < 786432 + 393216) {
        // ff_w1 [6][128][512] -> [6][512][128]
        const int rem = id - 786432;
        const int l = rem >> 16, r2 = rem & 65535;
        const int n = r2 >> 7, k = r2 & 127;
        f1d[rem] = f2bf(f1s[(size_t)l * 65536 + k * 512 + n]);
    } else if (id < 786432 + 786432) {
        // ff_w2 [6][512][128] -> [6][128][512]
        const int rem = id - 786432 - 393216;
        const int l = rem >> 16, r2 = rem & 65535;
        const int n = r2 >> 9, k = r2 & 511;
        f2d[rem] = f2bf(f2s[(size_t)l * 65536 + k * 128 + n]);
    } else {
        const int rem = id - 1572864;
        if (rem < 8192) {
            const int row = rem >> 5, pos = rem & 31;
            Vt[(size_t)row * VTJ + 1792 + pos] = 0;
        }
    }
}

// ---------------------------------------------------------------------------
// h = relu(latent @ lp_w1 + lp_b1)   [2, 256]
// ---------------------------------------------------------------------------
__global__ __launch_bounds__(256) void lat_h_kernel(
    const float* __restrict__ latent, const float* __restrict__ w1,
    const float* __restrict__ b1, float* __restrict__ h)
{
    __shared__ float ls[LATn];
    const int b = blockIdx.x;
    const int t = threadIdx.x;
    for (int k = t; k < LATn; k += 256) ls[k] = latent[b * LATn + k];
    __syncthreads();
    float acc = 0.f;
    #pragma unroll 8
    for (int k = 0; k < LATn; ++k) acc = fmaf(ls[k], w1[(size_t)k * 256 + t], acc);
    h[b * 256 + t] = fmaxf(acc + b1[t], 0.f);
}

// ---------------------------------------------------------------------------
// dec = h @ lp_w2 + lp_b2 + pos_encoding ; writes fp32 x and bf16 xb, encb
// ---------------------------------------------------------------------------
__global__ __launch_bounds__(256) void dec_kernel(
    const float* __restrict__ h, const float* __restrict__ w2,
    const float* __restrict__ b2, float* __restrict__ x,
    u16* __restrict__ xb, u16* __restrict__ encb)
{
    __shared__ float hs[512];
    const int t = threadIdx.x;
    hs[t] = h[t];
    hs[256 + t] = h[256 + t];
    __syncthreads();
    const int j = blockIdx.x * 256 + t;
    float a0 = 0.f, a1 = 0.f;
    #pragma unroll 8
    for (int k = 0; k < 256; ++k) {
        float w = w2[(size_t)k * SDn + j];
        a0 = fmaf(hs[k], w, a0);
        a1 = fmaf(hs[256 + k], w, a1);
    }
    const int s = j >> 7, d = j & 127;
    const int i2 = d >> 1;
    const float freq = __expf(-(float)(2 * i2) * (9.210340371976184f / 128.f));
    const float ang = (float)s * freq;
    const float pe = (d & 1) ? cosf(ang) : sinf(ang);
    const float bias = b2[j] + pe;
    const float v0 = a0 + bias;
    const float v1 = a1 + bias;
    x[j] = v0;
    x[SDn + j] = v1;
    xb[j] = f2bf(v0);    xb[SDn + j] = f2bf(v1);
    encb[j] = f2bf(v0);  encb[SDn + j] = f2bf(v1);
}

// ---------------------------------------------------------------------------
// QKV projection from a global bf16 activation (layer-0 self-attn only).
// ---------------------------------------------------------------------------
__global__ __launch_bounds__(256) void mm_qkv_kernel(
    const u16* __restrict__ Aq, const u16* __restrict__ Akv,
    const u16* __restrict__ Wq, const u16* __restrict__ Wk, const u16* __restrict__ Wv,
    const float* __restrict__ bq, const float* __restrict__ bk, const float* __restrict__ bv,
    u16* __restrict__ Qb, u16* __restrict__ Kb, u16* __restrict__ Vt)
{
    const int z = blockIdx.z;
    const u16* A = (z == 0) ? Aq : Akv;
    const u16* W = (z == 0) ? Wq : (z == 1) ? Wk : Wv;
    const float* Bi = (z == 0) ? bq : (z == 1) ? bk : bv;

    const int w = threadIdx.x >> 6;
    const int lane = threadIdx.x & 63;
    const int ql = lane & 31, hi = lane >> 5;
    const int m0 = blockIdx.x * 64 + (w & 1) * 32;
    const int nh = (w >> 1) * 64;

    f32x16 acc0 = (f32x16)0.0f, acc1 = (f32x16)0.0f;
    const size_t arow = (size_t)(m0 + ql) * 128;

    #pragma unroll
    for (int kk = 0; kk < 8; ++kk) {
        const short8 a = *(const short8*)(A + arow + kk * 16 + 8 * hi);
        const short8 b0 = *(const short8*)(W + (size_t)(nh + ql) * 128 + kk * 16 + 8 * hi);
        const short8 b1 = *(const short8*)(W + (size_t)(nh + 32 + ql) * 128 + kk * 16 + 8 * hi);
        acc0 = __builtin_amdgcn_mfma_f32_32x32x16_bf16(a, b0, acc0, 0, 0, 0);
        acc1 = __builtin_amdgcn_mfma_f32_32x32x16_bf16(a, b1, acc1, 0, 0, 0);
    }

    #pragma unroll
    for (int j = 0; j < 2; ++j) {
        const int n = nh + j * 32 + ql;
        const float bv_ = Bi[n];
        const int h = n >> 4, d = n & 15;
        #pragma unroll
        for (int r = 0; r < 16; ++r) {
            const int m = m0 + ROWMAP(r, hi);
            if (m >= BSn) continue;
            float v = (j ? acc1[r] : acc0[r]) + bv_;
            const int bq_ = (m >= Sn) ? 1 : 0;
            const int s = m - bq_ * Sn;
            const int bh = bq_ * 8 + h;
            if (z == 0) {
                Qb[((size_t)bh * Sn + s) * 16 + d] = f2bf(v * QSCALE);
            } else if (z == 1) {
                Kb[((size_t)bh * Sn + s) * 16 + d] = f2bf(v);
            } else {
                const int jt = s >> 5, sl = s & 31;
                Vt[((size_t)bh * 16 + d) * VTJ + jt * 32 + GPERM(sl)] = f2bf(v);
            }
        }
    }
}

// ---------------------------------------------------------------------------
// LN stats helper (256 threads, 32 rows x 128 cols in ls)
// ---------------------------------------------------------------------------
__device__ inline void ln_stats(const float* ls, float* mus, float* invs, int t)
{
    const int row = t >> 3, q = t & 7;
    float s1 = 0.f, s2 = 0.f;
    const float* lr = &ls[row * 132 + q * 16];
    #pragma unroll
    for (int c = 0; c < 16; c += 4) {
        const float4 v = *(const float4*)&lr[c];
        s1 += v.x + v.y + v.z + v.w;
        s2 += v.x * v.x + v.y * v.y + v.z * v.z + v.w * v.w;
    }
    s1 += __shfl_xor(s1, 1); s2 += __shfl_xor(s2, 1);
    s1 += __shfl_xor(s1, 2); s2 += __shfl_xor(s2, 2);
    s1 += __shfl_xor(s1, 4); s2 += __shfl_xor(s2, 4);
    const float mu = s1 * (1.f / 128.f);
    const float var = s2 * (1.f / 128.f) - mu * mu;
    if (q == 0) { mus[row] = mu; invs[row] = rsqrtf(var + 1e-5f); }
}

// ---------------------------------------------------------------------------
// K2: O-proj(self) + residual + LN1 -> x (fp32) & LDS y (bf16);
// then cross-attn QKV: Q = y@Wq, K/V = encb@Wk/Wv -> Qb, Kb, Vt.
// ---------------------------------------------------------------------------
__global__ __launch_bounds__(256) void fuse_oln_qkv_kernel(
    const u16* __restrict__ A, const u16* __restrict__ Wo,
    const float* __restrict__ bo,
    const float* __restrict__ g, const float* __restrict__ bb,
    float* __restrict__ X, const u16* __restrict__ Enc,
    const u16* __restrict__ Wq, const u16* __restrict__ Wk, const u16* __restrict__ Wv,
    const float* __restrict__ bq, const float* __restrict__ bk, const float* __restrict__ bv,
    u16* __restrict__ Qb, u16* __restrict__ Kb, u16* __restrict__ Vt)
{
    __shared__ float ls[32 * 132];
    __shared__ float mus[32], invs[32];
    __shared__ alignas(16) u16 ybuf[32][136];

    const int t = threadIdx.x;
    const int w = t >> 6, lane = t & 63;
    const int ql = lane & 31, hi = lane >> 5;
    const int m0 = blockIdx.x * 32;

    {
        f32x16 acc = (f32x16)0.0f;
        const size_t arow = (size_t)(m0 + ql) * 128;
        const int nh = w * 32;
        #pragma unroll
        for (int kk = 0; kk < 8; ++kk) {
            const short8 a = *(const short8*)(A + arow + kk * 16 + 8 * hi);
            const short8 b0 = *(const short8*)(Wo + (size_t)(nh + ql) * 128 + kk * 16 + 8 * hi);
            acc = __builtin_amdgcn_mfma_f32_32x32x16_bf16(a, b0, acc, 0, 0, 0);
        }
        const int n = nh + ql;
        const float bv_ = bo[n];
        #pragma unroll
        for (int r = 0; r < 16; ++r) {
            const int row = ROWMAP(r, hi);
            const int gm = m0 + row;
            float v = acc[r] + bv_;
            if (gm < BSn) v += X[(size_t)gm * 128 + n];
            ls[row * 132 + n] = v;
        }
    }
    __syncthreads();
    ln_stats(ls, mus, invs, t);
    __syncthreads();
    #pragma unroll
    for (int it = 0; it < 4; ++it) {
        const int idx = it * 256 + t;
        const int row = idx >> 5, cg = (idx & 31) * 4;
        const int gm = m0 + row;
        const float4 v = *(const float4*)&ls[row * 132 + cg];
        const float mu = mus[row], inv = invs[row];
        const float4 gv = *(const float4*)&g[cg];
        const float4 bv2 = *(const float4*)&bb[cg];
        float4 y;
        y.x = (v.x - mu) * inv * gv.x + bv2.x;
        y.y = (v.y - mu) * inv * gv.y + bv2.y;
        y.z = (v.z - mu) * inv * gv.z + bv2.z;
        y.w = (v.w - mu) * inv * gv.w + bv2.w;
        if (gm < BSn) *(float4*)&X[(size_t)gm * 128 + cg] = y;
        uint2 u;
        u.x = cvtpk_bf16(y.x, y.y);
        u.y = cvtpk_bf16(y.z, y.w);
        *(uint2*)&ybuf[row][cg] = u;
    }
    __syncthreads();

    #pragma unroll
    for (int z = 0; z < 3; ++z) {
        const u16* W = (z == 0) ? Wq : (z == 1) ? Wk : Wv;
        const float* Bi = (z == 0) ? bq : (z == 1) ? bk : bv;
        f32x16 acc = (f32x16)0.0f;
        const int nh = w * 32;
        #pragma unroll
        for (int kk = 0; kk < 8; ++kk) {
            short8 a;
            if (z == 0) a = *(const short8*)&ybuf[ql][kk * 16 + 8 * hi];
            else        a = *(const short8*)(Enc + (size_t)(m0 + ql) * 128 + kk * 16 + 8 * hi);
            const short8 b0 = *(const short8*)(W + (size_t)(nh + ql) * 128 + kk * 16 + 8 * hi);
            acc = __builtin_amdgcn_mfma_f32_32x32x16_bf16(a, b0, acc, 0, 0, 0);
        }
        const int n = nh + ql;
        const float bv_ = Bi[n];
        const int h = n >> 4, d = n & 15;
        #pragma unroll
        for (int r = 0; r < 16; ++r) {
            const int m = m0 + ROWMAP(r, hi);
            if (m >= BSn) continue;
            float v = acc[r] + bv_;
            const int bq_ = (m >= Sn) ? 1 : 0;
            const int s = m - bq_ * Sn;
            const int bh = bq_ * 8 + h;
            if (z == 0)      Qb[((size_t)bh * Sn + s) * 16 + d] = f2bf(v * QSCALE);
            else if (z == 1) Kb[((size_t)bh * Sn + s) * 16 + d] = f2bf(v);
            else             Vt[((size_t)bh * 16 + d) * VTJ + (s >> 5) * 32 + GPERM(s & 31)] = f2bf(v);
        }
    }
}

// ---------------------------------------------------------------------------
// K4: O-proj(cross) + residual + LN2 + FF1 + FF2 + residual + LN3 -> x;
// then (if WITH_QKV) next layer's self-attn QKV.
// ---------------------------------------------------------------------------
template <int WITH_QKV>
__global__ __launch_bounds__(256) void fuse_ffn_kernel(
    const u16* __restrict__ A, const u16* __restrict__ Wo,
    const float* __restrict__ bo,
    const float* __restrict__ g2, const float* __restrict__ b2ln,
    const u16* __restrict__ W1, const float* __restrict__ b1,
    const u16* __restrict__ W2, const float* __restrict__ b2f,
    const float* __restrict__ g3, const float* __restrict__ b3ln,
    float* __restrict__ X,
    const u16* __restrict__ Wq, const u16* __restrict__ Wk, const u16* __restrict__ Wv,
    const float* __restrict__ bq, const float* __restrict__ bk, const float* __restrict__ bv,
    u16* __restrict__ Qb, u16* __restrict__ Kb, u16* __restrict__ Vt)
{
    __shared__ float ls[32 * 132];
    __shared__ float mus[32], invs[32];
    __shared__ alignas(16) u16 ybuf[32][136];
    __shared__ alignas(16) u16 hbuf[32][536];

    const int t = threadIdx.x;
    const int w = t >> 6, lane = t & 63;
    const int ql = lane & 31, hi = lane >> 5;
    const int m0 = blockIdx.x * 32;

    {
        f32x16 acc = (f32x16)0.0f;
        const size_t arow = (size_t)(m0 + ql) * 128;
        const int nh = w * 32;
        #pragma unroll
        for (int kk = 0; kk < 8; ++kk) {
            const short8 a = *(const short8*)(A + arow + kk * 16 + 8 * hi);
            const short8 b0 = *(const short8*)(Wo + (size_t)(nh + ql) * 128 + kk * 16 + 8 * hi);
            acc = __builtin_amdgcn_mfma_f32_32x32x16_bf16(a, b0, acc, 0, 0, 0);
        }
        const int n = nh + ql;
        const float bv_ = bo[n];
        #pragma unroll
        for (int r = 0; r < 16; ++r) {
            const int row = ROWMAP(r, hi);
            const int gm = m0 + row;
            float v = acc[r] + bv_;
            if (gm < BSn) v += X[(size_t)gm * 128 + n];
            ls[row * 132 + n] = v;
        }
    }
    __syncthreads();
    ln_stats(ls, mus, invs, t);
    __syncthreads();
    #pragma unroll
    for (int it = 0; it < 4; ++it) {
        const int idx = it * 256 + t;
        const int row = idx >> 5, cg = (idx & 31) * 4;
        const float4 v = *(const float4*)&ls[row * 132 + cg];
        const float mu = mus[row], inv = invs[row];
        const float4 gv = *(const float4*)&g2[cg];
        const float4 bv2 = *(const float4*)&b2ln[cg];
        float4 y;
        y.x = (v.x - mu) * inv * gv.x + bv2.x;
        y.y = (v.y - mu) * inv * gv.y + bv2.y;
        y.z = (v.z - mu) * inv * gv.z + bv2.z;
        y.w = (v.w - mu) * inv * gv.w + bv2.w;
        *(float4*)&ls[row * 132 + cg] = y;
        uint2 u;
        u.x = cvtpk_bf16(y.x, y.y);
        u.y = cvtpk_bf16(y.z, y.w);
        *(uint2*)&ybuf[row][cg] = u;
    }
    __syncthreads();

    #pragma unroll
    for (int nt = 0; nt < 4; ++nt) {
        const int n0 = w * 128 + nt * 32;
        f32x16 acc = (f32x16)0.0f;
        #pragma unroll
        for (int kk = 0; kk < 8; ++kk) {
            const short8 a = *(const short8*)&ybuf[ql][kk * 16 + 8 * hi];
            const short8 b0 = *(const short8*)(W1 + (size_t)(n0 + ql) * 128 + kk * 16 + 8 * hi);
            acc = __builtin_amdgcn_mfma_f32_32x32x16_bf16(a, b0, acc, 0, 0, 0);
        }
        const int n = n0 + ql;
        const float bv_ = b1[n];
        #pragma unroll
        for (int r = 0; r < 16; ++r) {
            const int row = ROWMAP(r, hi);
            hbuf[row][n] = f2bf(fmaxf(acc[r] + bv_, 0.f));
        }
    }
    __syncthreads();

    {
        f32x16 acc = (f32x16)0.0f;
        const int nh = w * 32;
        #pragma unroll
        for (int kk = 0; kk < 32; ++kk) {
            const short8 a = *(const short8*)&hbuf[ql][kk * 16 + 8 * hi];
            const short8 b0 = *(const short8*)(W2 + (size_t)(nh + ql) * 512 + kk * 16 + 8 * hi);
            acc = __builtin_amdgcn_mfma_f32_32x32x16_bf16(a, b0, acc, 0, 0, 0);
        }
        const int n = nh + ql;
        const float bv_ = b2f[n];
        #pragma unroll
        for (int r = 0; r < 16; ++r) {
            const int row = ROWMAP(r, hi);
            ls[row * 132 + n] = acc[r] + bv_ + ls[row * 132 + n];
        }
    }
    __syncthreads();
    ln_stats(ls, mus, invs, t);
    __syncthreads();
    #pragma unroll
    for (int it = 0; it < 4; ++it) {
        const int idx = it * 256 + t;
        const int row = idx >> 5, cg = (idx & 31) * 4;
        const int gm = m0 + row;
        const float4 v = *(const float4*)&ls[row * 132 + cg];
        const float mu = mus[row], inv = invs[row];
        const float4 gv = *(const float4*)&g3[cg];
        const float4 bv2 = *(const float4*)&b3ln[cg];
        float4 y;
        y.x = (v.x - mu) * inv * gv.x + bv2.x;
        y.y = (v.y - mu) * inv * gv.y + bv2.y;
        y.z = (v.z - mu) * inv * gv.z + bv2.z;
        y.w = (v.w - mu) * inv * gv.w + bv2.w;
        if (gm < BSn) *(float4*)&X[(size_t)gm * 128 + cg] = y;
        uint2 u;
        u.x = cvtpk_bf16(y.x, y.y);
        u.y = cvtpk_bf16(y.z, y.w);
        *(uint2*)&ybuf[row][cg] = u;
    }

    if (WITH_QKV) {
        __syncthreads();
        #pragma unroll
        for (int z = 0; z < 3; ++z) {
            const u16* W = (z == 0) ? Wq : (z == 1) ? Wk : Wv;
            const float* Bi = (z == 0) ? bq : (z == 1) ? bk : bv;
            f32x16 acc = (f32x16)0.0f;
            const int nh = w * 32;
            #pragma unroll
            for (int kk = 0; kk < 8; ++kk) {
                const short8 a = *(const short8*)&ybuf[ql][kk * 16 + 8 * hi];
                const short8 b0 = *(const short8*)(W + (size_t)(nh + ql) * 128 + kk * 16 + 8 * hi);
                acc = __builtin_amdgcn_mfma_f32_32x32x16_bf16(a, b0, acc, 0, 0, 0);
            }
            const int n = nh + ql;
            const float bv_ = Bi[n];
            const int h = n >> 4, d = n & 15;
            #pragma unroll
            for (int r = 0; r < 16; ++r) {
                const int m = m0 + ROWMAP(r, hi);
                if (m >= BSn) continue;
                float v = acc[r] + bv_;
                const int bq_ = (m >= Sn) ? 1 : 0;
                const int s = m - bq_ * Sn;
                const int bh = bq_ * 8 + h;
                if (z == 0)      Qb[((size_t)bh * Sn + s) * 16 + d] = f2bf(v * QSCALE);
                else if (z == 1) Kb[((size_t)bh * Sn + s) * 16 + d] = f2bf(v);
                else             Vt[((size_t)bh * 16 + d) * VTJ + (s >> 5) * 32 + GPERM(s & 31)] = f2bf(v);
            }
        }
    }
}

// ---------------------------------------------------------------------------
// MFMA flash attention, 8-way split-KV (512 threads), exp2-domain softmax.
// Proven single-tile loop body; only the split width and merge changed.
// ---------------------------------------------------------------------------
template <int MASK>
__global__ __launch_bounds__(512) void flash_mfma(
    const u16* __restrict__ Qb, const u16* __restrict__ Kb,
    const u16* __restrict__ Vt, u16* __restrict__ Ob)
{
    __shared__ float mrg[8][64][10];

    const int wid = threadIdx.x >> 6;
    const int lane = threadIdx.x & 63;
    const int bh = blockIdx.y;
    const int b = bh >> 3, h = bh & 7;

    if (MASK && blockIdx.x == NQT) {
        // row 1799: uniform softmax over all 1800 -> mean of V (32 partials)
        const int d = threadIdx.x & 15, part = threadIdx.x >> 4;   // part in [0,32)
        const u16* row = Vt + ((size_t)bh * 16 + d) * VTJ;
        float s = 0.f;
        for (int j = part; j < VTJ; j += 32) s += bf2f(row[j]);
        ((float*)mrg)[part * 16 + d] = s;
        __syncthreads();
        if (threadIdx.x < 16) {
            float tot = 0.f;
            #pragma unroll
            for (int p = 0; p < 32; ++p) tot += ((float*)mrg)[p * 16 + threadIdx.x];
            Ob[((size_t)(b * Sn + (Sn - 1))) * 128 + h * 16 + threadIdx.x] =
                f2bf(tot * (1.f / (float)Sn));
        }
        return;
    }

    const int ql = lane & 31, hi = lane >> 5;
    const int qt = blockIdx.x;
    const int qrow = qt * 32 + ql;
    const int qr = (qrow < Sn) ? qrow : (Sn - 1);
    const short8 qf = *(const short8*)(Qb + ((size_t)bh * Sn + qr) * 16 + 8 * hi);
    const u16* kbase = Kb + (size_t)bh * Sn * 16;
    const u16* vbase = Vt + ((size_t)bh * 16 + (ql & 15)) * VTJ;

    f32x16 acc = (f32x16)0.0f;
    float m = -INFINITY, lsum = 0.f;

    int jt = (MASK ? qt : 0) + wid;
    short8 kf = (short8)0, va = (short8)0, vb2 = (short8)0;
    if (jt < NQT) {
        int krow = jt * 32 + ql; if (krow >= Sn) krow = Sn - 1;
        kf  = *(const short8*)(kbase + (size_t)krow * 16 + 8 * hi);
        va  = *(const short8*)(vbase + jt * 32 + 8 * hi);
        vb2 = *(const short8*)(vbase + jt * 32 + 16 + 8 * hi);
    }

    for (; jt < NQT; jt += 8) {
        short8 kn = kf, van = va, vbn = vb2;
        if (jt + 8 < NQT) {
            int nrow = (jt + 8) * 32 + ql; if (nrow >= Sn) nrow = Sn - 1;
            kn  = *(const short8*)(kbase + (size_t)nrow * 16 + 8 * hi);
            van = *(const short8*)(vbase + (jt + 8) * 32 + 8 * hi);
            vbn = *(const short8*)(vbase + (jt + 8) * 32 + 16 + 8 * hi);
        }

        const f32x16 sc = __builtin_amdgcn_mfma_f32_32x32x16_bf16(kf, qf, (f32x16)0.0f, 0, 0, 0);

        float sv[16];
        #pragma unroll
        for (int r = 0; r < 16; ++r) sv[r] = sc[r];

        if (MASK && jt == qt) {     // only wave 0 ever hits jt == qt
            #pragma unroll
            for (int r = 0; r < 16; ++r)
                if (!(ROWMAP(r, hi) > ql)) sv[r] = -1e9f;
        }
        if (jt == NQT - 1) {
            #pragma unroll
            for (int r = 0; r < 16; ++r)
                if (1792 + ROWMAP(r, hi) >= Sn) sv[r] = -1e30f;
        }

        // depth-3 max tree (v_max3 fusible)
        const float a0 = fmaxf(fmaxf(sv[0], sv[1]), sv[2]);
        const float a1 = fmaxf(fmaxf(sv[3], sv[4]), sv[5]);
        const float a2 = fmaxf(fmaxf(sv[6], sv[7]), sv[8]);
        const float a3 = fmaxf(fmaxf(sv[9], sv[10]), sv[11]);
        const float a4 = fmaxf(fmaxf(sv[12], sv[13]), sv[14]);
        const float b0m = fmaxf(fmaxf(a0, a1), a2);
        const float b1m = fmaxf(fmaxf(a3, a4), sv[15]);
        const float tmax = xhalf_max(fmaxf(b0m, b1m));

        // unconditional online-softmax rescale
        const float mnew = fmaxf(m, tmax);
        const float corr = EXP2(m - mnew);
        m = mnew;
        lsum *= corr;
        #pragma unroll
        for (int r = 0; r < 16; ++r) acc[r] *= corr;

        float p[16];
        float ps = 0.f;
        #pragma unroll
        for (int r = 0; r < 16; ++r) { p[r] = EXP2(sv[r] - m); ps += p[r]; }
        lsum += ps;

        union { u32 u[4]; short8 s; } B0c, B1c;
        B0c.u[0] = cvtpk_bf16(p[0],  p[1]);  B0c.u[1] = cvtpk_bf16(p[2],  p[3]);
        B0c.u[2] = cvtpk_bf16(p[4],  p[5]);  B0c.u[3] = cvtpk_bf16(p[6],  p[7]);
        B1c.u[0] = cvtpk_bf16(p[8],  p[9]);  B1c.u[1] = cvtpk_bf16(p[10], p[11]);
        B1c.u[2] = cvtpk_bf16(p[12], p[13]); B1c.u[3] = cvtpk_bf16(p[14], p[15]);

        acc = __builtin_amdgcn_mfma_f32_32x32x16_bf16(va,  B0c.s, acc, 0, 0, 0);
        acc = __builtin_amdgcn_mfma_f32_32x32x16_bf16(vb2, B1c.s, acc, 0, 0, 0);

        kf = kn; va = van; vb2 = vbn;
    }

    mrg[wid][lane][0] = m;
    mrg[wid][lane][1] = lsum;
    #pragma unroll
    for (int r = 0; r < 8; ++r) mrg[wid][lane][2 + r] = acc[r];
    __syncthreads();

    if (wid == 0) {
        float mstar = mrg[0][lane][0];
        #pragma unroll
        for (int w2 = 1; w2 < 8; ++w2) mstar = fmaxf(mstar, mrg[w2][lane][0]);
        float lt = 0.f;
        float accf[8] = {};
        #pragma unroll
        for (int w2 = 0; w2 < 8; ++w2) {
            const float sc2 = EXP2(mrg[w2][lane][0] - mstar);
            lt += mrg[w2][lane][1] * sc2;
            #pragma unroll
            for (int r = 0; r < 8; ++r) accf[r] = fmaf(mrg[w2][lane][2 + r], sc2, accf[r]);
        }
        const float ltot = xhalf_sum(lt);
        const float inv = 1.f / ltot;
        if (qrow < Sn && !(MASK && qrow == Sn - 1)) {
            u16* op = Ob + ((size_t)(b * Sn + qrow)) * 128 + h * 16;
            uint2 u0, u1;
            u0.x = cvtpk_bf16(accf[0] * inv, accf[1] * inv);
            u0.y = cvtpk_bf16(accf[2] * inv, accf[3] * inv);
            u1.x = cvtpk_bf16(accf[4] * inv, accf[5] * inv);
            u1.y = cvtpk_bf16(accf[6] * inv, accf[7] * inv);
            *(uint2*)(op + 4 * hi) = u0;
            *(uint2*)(op + 8 + 4 * hi) = u1;
        }
    }
}

// ---------------------------------------------------------------------------
// logits = x @ out_w + out_b   [3600,128]@[128,16]  (fp32)
// ---------------------------------------------------------------------------
__global__ __launch_bounds__(256) void out_kernel(
    const float* __restrict__ X, const float* __restrict__ W,
    const float* __restrict__ bb, float* __restrict__ out)
{
    const int t = threadIdx.x;
    const int n = t & 15;
    const int r = blockIdx.x * 16 + (t >> 4);
    if (r >= BSn) return;
    float acc = 0.f;
    #pragma unroll 8
    for (int k = 0; k < 128; ++k)
        acc = fmaf(X[(size_t)r * 128 + k], W[k * 16 + n], acc);
    out[(size_t)r * 16 + n] = acc + bb[n];
}

// ---------------------------------------------------------------------------
extern "C" void kernel_launch(void* const* d_in, const int* in_sizes, int n_in,
                              void* d_out, int out_size, void* d_ws, size_t ws_size,
                              hipStream_t stream)
{
    const float* latent = (const float*)d_in[0];
    const float* lp_w1  = (const float*)d_in[1];
    const float* lp_b1  = (const float*)d_in[2];
    const float* lp_w2  = (const float*)d_in[3];
    const float* lp_b2  = (const float*)d_in[4];
    const float* out_w  = (const float*)d_in[5];
    const float* out_b  = (const float*)d_in[6];
    const float* sa_wq = (const float*)d_in[7];  const float* sa_bq = (const float*)d_in[8];
    const float* sa_wk = (const float*)d_in[9];  const float* sa_bk = (const float*)d_in[10];
    const float* sa_wv = (const float*)d_in[11]; const float* sa_bv = (const float*)d_in[12];
    const float* sa_wo = (const float*)d_in[13]; const float* sa_bo = (const float*)d_in[14];
    const float* ca_wq = (const float*)d_in[15]; const float* ca_bq = (const float*)d_in[16];
    const float* ca_wk = (const float*)d_in[17]; const float* ca_bk = (const float*)d_in[18];
    const float* ca_wv = (const float*)d_in[19]; const float* ca_bv = (const float*)d_in[20];
    const float* ca_wo = (const float*)d_in[21]; const float* ca_bo = (const float*)d_in[22];
    const float* ff_w1 = (const float*)d_in[23]; const float* ff_b1 = (const float*)d_in[24];
    const float* ff_w2 = (const float*)d_in[25]; const float* ff_b2 = (const float*)d_in[26];
    const float* ln1g = (const float*)d_in[27]; const float* ln1b = (const float*)d_in[28];
    const float* ln2g = (const float*)d_in[29]; const float* ln2b = (const float*)d_in[30];
    const float* ln3g = (const float*)d_in[31]; const float* ln3b = (const float*)d_in[32];

    float* ws = (float*)d_ws;
    float* x    = ws;                         // 460800 f
    float* hlat = ws + 460800;                // 512 f
    u16* xb   = (u16*)(ws + 461312);          // MPAD*128 us = 237568 f (layer-0 only)
    u16* encb = (u16*)(ws + 698880);          // 237568 f
    u16* ob   = (u16*)(ws + 936448);          // 237568 f
    u16* Qb   = (u16*)(ws + 2124288);         // 230400 f   (slack layout: load-bearing)
    u16* Kb   = (u16*)(ws + 2354688);         // 230400 f
    u16* Vt   = (u16*)(ws + 2585088);         // 16*16*1824 us = 233472 f
    u16* wt_saq = (u16*)(ws + 2818560);       // 8 square mats, 49152 f each
    u16* wt_sak = wt_saq + 6 * 16384;
    u16* wt_sav = wt_sak + 6 * 16384;
    u16* wt_sao = wt_sav + 6 * 16384;
    u16* wt_caq = wt_sao + 6 * 16384;
    u16* wt_cak = wt_caq + 6 * 16384;
    u16* wt_cav = wt_cak + 6 * 16384;
    u16* wt_cao = wt_cav + 6 * 16384;
    u16* wt1  = (u16*)(ws + 3211776);         // [6][512][128] us = 196608 f
    u16* wt2  = (u16*)(ws + 3408384);         // [6][128][512] us = 196608 f

    wprep_kernel<<<dim3(6176), dim3(256), 0, stream>>>(
        sa_wq, sa_wk, sa_wv, sa_wo, ca_wq, ca_wk, ca_wv, ca_wo,
        wt_saq, wt_sak, wt_sav, wt_sao, wt_caq, wt_cak, wt_cav, wt_cao,
        ff_w1, wt1, ff_w2, wt2, Vt);

    lat_h_kernel<<<dim3(2), dim3(256), 0, stream>>>(latent, lp_w1, lp_b1, hlat);
    dec_kernel<<<dim3(900), dim3(256), 0, stream>>>(hlat, lp_w2, lp_b2, x, xb, encb);

    const dim3 thr(256), thrF(512);
    const dim3 gFm(NQT + 1, 16), gFc(NQT, 16), gFuse(113);

    // layer-0 self-attn QKV from xb
    mm_qkv_kernel<<<dim3(57, 1, 3), thr, 0, stream>>>(
        xb, xb, wt_saq, wt_sak, wt_sav, sa_bq, sa_bk, sa_bv, Qb, Kb, Vt);

    for (int i = 0; i < Ln; ++i) {
        const size_t wOff = (size_t)i * 16384;
        const size_t bOff = (size_t)i * 128;
        const size_t fOff = (size_t)i * 65536;
        const size_t f1b  = (size_t)i * 512;
        const size_t wNxt = (size_t)(i + 1) * 16384;
        const size_t bNxt = (size_t)(i + 1) * 128;

        flash_mfma<1><<<gFm, thrF, 0, stream>>>(Qb, Kb, Vt, ob);

        fuse_oln_qkv_kernel<<<gFuse, thr, 0, stream>>>(
            ob, wt_sao + wOff, sa_bo + bOff, ln1g + bOff, ln1b + bOff, x, encb,
            wt_caq + wOff, wt_cak + wOff, wt_cav + wOff,
            ca_bq + bOff, ca_bk + bOff, ca_bv + bOff, Qb, Kb, Vt);

        flash_mfma<0><<<gFc, thrF, 0, stream>>>(Qb, Kb, Vt, ob);

        if (i < Ln - 1) {
            fuse_ffn_kernel<1><<<gFuse, thr, 0, stream>>>(
                ob, wt_cao + wOff, ca_bo + bOff, ln2g + bOff, ln2b + bOff,
                wt1 + fOff, ff_b1 + f1b, wt2 + fOff, ff_b2 + bOff,
                ln3g + bOff, ln3b + bOff, x,
                wt_saq + wNxt, wt_sak + wNxt, wt_sav + wNxt,
                sa_bq + bNxt, sa_bk + bNxt, sa_bv + bNxt, Qb, Kb, Vt);
        } else {
            fuse_ffn_kernel<0><<<gFuse, thr, 0, stream>>>(
                ob, wt_cao + wOff, ca_bo + bOff, ln2g + bOff, ln2b + bOff,
                wt1 + fOff, ff_b1 + f1b, wt2 + fOff, ff_b2 + bOff,
                ln3g + bOff, ln3b + bOff, x,
                wt_saq, wt_sak, wt_sav, sa_bq, sa_bk, sa_bv, Qb, Kb, Vt);
        }
    }

    out_kernel<<<dim3(225), dim3(256), 0, stream>>>(x, out_w, out_b, (float*)d_out);
}

// Round 17
// 590.689 us; speedup vs baseline: 1.0697x; 1.0007x over previous
//
#include <hip/hip_runtime.h>
#include <hip/hip_bf16.h>
#include <math.h>

// Problem constants
#define Bn   2
#define Sn   1800
#define Dn   128
#define Hn   8
#define DKn  16
#define DFFn 512
#define Ln   6
#define Vn   16
#define LATn 1024
#define BSn  3600        // B*S
#define SDn  230400      // S*D
#define NQT  57          // ceil(1800/32)
#define VTJ  1824        // padded j-dim of transposed V
#define MPAD 3712        // padded row count for bf16 activation buffers

// Q pre-scale: 1/sqrt(16) * log2(e)  -> softmax runs in exp2 domain
#define QSCALE 0.3606737602222409f

typedef __attribute__((ext_vector_type(8))) short short8;   // 8 bf16 = 4 VGPR
typedef __attribute__((ext_vector_type(16))) float f32x16;
typedef unsigned int u32;
typedef unsigned short u16;

// MFMA 32x32x16 C/D layout: row = (reg&3) + 8*(reg>>2) + 4*hi, col = lane&31
#define ROWMAP(r, hi) (((r) & 3) + 8 * ((r) >> 2) + 4 * (hi))
// V-column permutation so PV's B-fragment needs no cross-lane exchange
#define GPERM(sl) (((sl) & 3) + (((sl) & 4) << 1) + (((sl) & 8) >> 1) + ((sl) & 16))

// native hardware exp2 (v_exp_f32); exp2f() lowers to the slow OCML call.
#define EXP2(x) __builtin_amdgcn_exp2f(x)

__device__ inline u32 cvtpk_bf16(float a, float b) {
    u32 r;
    asm("v_cvt_pk_bf16_f32 %0, %1, %2" : "=v"(r) : "v"(a), "v"(b));
    return r;
}

__device__ inline u16 f2bf(float f) {
    union { float f; u32 u; } x; x.f = f;
    u32 r = (x.u + 0x7FFFu + ((x.u >> 16) & 1u)) >> 16;
    return (u16)r;
}

__device__ inline float bf2f(u16 v) {
    union { u32 u; float f; } x; x.u = ((u32)v) << 16;
    return x.f;
}

// cross-half (lane <-> lane+32) combine. Proven primitive.
__device__ inline float xhalf_max(float t) {
    return fmaxf(t, __shfl_xor(t, 32));
}
__device__ inline float xhalf_sum(float t) {
    return t + __shfl_xor(t, 32);
}

// ---------------------------------------------------------------------------
// One-shot weight prep: 8 square mats transposed->bf16, ff_w1, ff_w2, Vt pad.
// Flat index space, grid 6176 x 256.
// ---------------------------------------------------------------------------
__global__ __launch_bounds__(256) void wprep_kernel(
    const float* __restrict__ s0, const float* __restrict__ s1,
    const float* __restrict__ s2, const float* __restrict__ s3,
    const float* __restrict__ s4, const float* __restrict__ s5,
    const float* __restrict__ s6, const float* __restrict__ s7,
    u16* __restrict__ d0, u16* __restrict__ d1, u16* __restrict__ d2,
    u16* __restrict__ d3, u16* __restrict__ d4, u16* __restrict__ d5,
    u16* __restrict__ d6, u16* __restrict__ d7,
    const float* __restrict__ f1s, u16* __restrict__ f1d,
    const float* __restrict__ f2s, u16* __restrict__ f2d,
    u16* __restrict__ Vt)
{
    const int id = blockIdx.x * 256 + threadIdx.x;
    if (id < 786432) {
        // 8 square mats [6][128][128]: dst[l][n][k] = src[l][k][n]
        const int z = id / 98304, rem = id % 98304;
        const float* src = (z == 0) ? s0 : (z == 1) ? s1 : (z == 2) ? s2 : (z == 3) ? s3
                         : (z == 4) ? s4 : (z == 5) ? s5 : (z == 6) ? s6 : s7;
        u16* dst = (z == 0) ? d0 : (z == 1) ? d1 : (z == 2) ? d2 : (z == 3) ? d3
                 : (z == 4) ? d4 : (z == 5) ? d5 : (z == 6) ? d6 : d7;
        const int l = rem >> 14, r2 = rem & 16383;
        const int n = r2 >> 7, k = r2 & 127;
        dst[rem] = f2bf(src[l * 16384 + k * 128 + n]);
    } else if (id < 786432 + 393216) {
        // ff_w1 [6][128][512] -> [6][512][128]
        const int rem = id - 786432;
        const int l = rem >> 16, r2 = rem & 65535;
        const int n = r2 >> 7, k = r2 & 127;
        f1d[rem] = f2bf(f1s[(size_t)l * 65536 + k * 512 + n]);
    } else if (id < 786432 + 786432) {
        // ff_w2 [6][512][128] -> [6][128][512]
        const int rem = id - 786432 - 393216;
        const int l = rem >> 16, r2 = rem & 65535;
        const int n = r2 >> 9, k = r2 & 511;
        f2d[rem] = f2bf(f2s[(size_t)l * 65536 + k * 128 + n]);
    } else {
        const int rem = id - 1572864;
        if (rem < 8192) {
            const int row = rem >> 5, pos = rem & 31;
            Vt[(size_t)row * VTJ + 1792 + pos] = 0;
        }
    }
}

// ---------------------------------------------------------------------------
// h = relu(latent @ lp_w1 + lp_b1)   [2, 256]
// ---------------------------------------------------------------------------
__global__ __launch_bounds__(256) void lat_h_kernel(
    const float* __restrict__ latent, const float* __restrict__ w1,
    const float* __restrict__ b1, float* __restrict__ h)
{
    __shared__ float ls[LATn];
    const int b = blockIdx.x;
    const int t = threadIdx.x;
    for (int k = t; k < LATn; k += 256) ls[k] = latent[b * LATn + k];
    __syncthreads();
    float acc = 0.f;
    #pragma unroll 8
    for (int k = 0; k < LATn; ++k) acc = fmaf(ls[k], w1[(size_t)k * 256 + t], acc);
    h[b * 256 + t] = fmaxf(acc + b1[t], 0.f);
}

// ---------------------------------------------------------------------------
// dec = h @ lp_w2 + lp_b2 + pos_encoding ; writes fp32 x and bf16 xb, encb
// ---------------------------------------------------------------------------
__global__ __launch_bounds__(256) void dec_kernel(
    const float* __restrict__ h, const float* __restrict__ w2,
    const float* __restrict__ b2, float* __restrict__ x,
    u16* __restrict__ xb, u16* __restrict__ encb)
{
    __shared__ float hs[512];
    const int t = threadIdx.x;
    hs[t] = h[t];
    hs[256 + t] = h[256 + t];
    __syncthreads();
    const int j = blockIdx.x * 256 + t;
    float a0 = 0.f, a1 = 0.f;
    #pragma unroll 8
    for (int k = 0; k < 256; ++k) {
        float w = w2[(size_t)k * SDn + j];
        a0 = fmaf(hs[k], w, a0);
        a1 = fmaf(hs[256 + k], w, a1);
    }
    const int s = j >> 7, d = j & 127;
    const int i2 = d >> 1;
    const float freq = __expf(-(float)(2 * i2) * (9.210340371976184f / 128.f));
    const float ang = (float)s * freq;
    const float pe = (d & 1) ? cosf(ang) : sinf(ang);
    const float bias = b2[j] + pe;
    const float v0 = a0 + bias;
    const float v1 = a1 + bias;
    x[j] = v0;
    x[SDn + j] = v1;
    xb[j] = f2bf(v0);    xb[SDn + j] = f2bf(v1);
    encb[j] = f2bf(v0);  encb[SDn + j] = f2bf(v1);
}

// ---------------------------------------------------------------------------
// QKV projection from a global bf16 activation (layer-0 self-attn only).
// ---------------------------------------------------------------------------
__global__ __launch_bounds__(256) void mm_qkv_kernel(
    const u16* __restrict__ Aq, const u16* __restrict__ Akv,
    const u16* __restrict__ Wq, const u16* __restrict__ Wk, const u16* __restrict__ Wv,
    const float* __restrict__ bq, const float* __restrict__ bk, const float* __restrict__ bv,
    u16* __restrict__ Qb, u16* __restrict__ Kb, u16* __restrict__ Vt)
{
    const int z = blockIdx.z;
    const u16* A = (z == 0) ? Aq : Akv;
    const u16* W = (z == 0) ? Wq : (z == 1) ? Wk : Wv;
    const float* Bi = (z == 0) ? bq : (z == 1) ? bk : bv;

    const int w = threadIdx.x >> 6;
    const int lane = threadIdx.x & 63;
    const int ql = lane & 31, hi = lane >> 5;
    const int m0 = blockIdx.x * 64 + (w & 1) * 32;
    const int nh = (w >> 1) * 64;

    f32x16 acc0 = (f32x16)0.0f, acc1 = (f32x16)0.0f;
    const size_t arow = (size_t)(m0 + ql) * 128;

    #pragma unroll
    for (int kk = 0; kk < 8; ++kk) {
        const short8 a = *(const short8*)(A + arow + kk * 16 + 8 * hi);
        const short8 b0 = *(const short8*)(W + (size_t)(nh + ql) * 128 + kk * 16 + 8 * hi);
        const short8 b1 = *(const short8*)(W + (size_t)(nh + 32 + ql) * 128 + kk * 16 + 8 * hi);
        acc0 = __builtin_amdgcn_mfma_f32_32x32x16_bf16(a, b0, acc0, 0, 0, 0);
        acc1 = __builtin_amdgcn_mfma_f32_32x32x16_bf16(a, b1, acc1, 0, 0, 0);
    }

    #pragma unroll
    for (int j = 0; j < 2; ++j) {
        const int n = nh + j * 32 + ql;
        const float bv_ = Bi[n];
        const int h = n >> 4, d = n & 15;
        #pragma unroll
        for (int r = 0; r < 16; ++r) {
            const int m = m0 + ROWMAP(r, hi);
            if (m >= BSn) continue;
            float v = (j ? acc1[r] : acc0[r]) + bv_;
            const int bq_ = (m >= Sn) ? 1 : 0;
            const int s = m - bq_ * Sn;
            const int bh = bq_ * 8 + h;
            if (z == 0) {
                Qb[((size_t)bh * Sn + s) * 16 + d] = f2bf(v * QSCALE);
            } else if (z == 1) {
                Kb[((size_t)bh * Sn + s) * 16 + d] = f2bf(v);
            } else {
                const int jt = s >> 5, sl = s & 31;
                Vt[((size_t)bh * 16 + d) * VTJ + jt * 32 + GPERM(sl)] = f2bf(v);
            }
        }
    }
}

// ---------------------------------------------------------------------------
// LN stats helper (256 threads, 32 rows x 128 cols in ls)
// ---------------------------------------------------------------------------
__device__ inline void ln_stats(const float* ls, float* mus, float* invs, int t)
{
    const int row = t >> 3, q = t & 7;
    float s1 = 0.f, s2 = 0.f;
    const float* lr = &ls[row * 132 + q * 16];
    #pragma unroll
    for (int c = 0; c < 16; c += 4) {
        const float4 v = *(const float4*)&lr[c];
        s1 += v.x + v.y + v.z + v.w;
        s2 += v.x * v.x + v.y * v.y + v.z * v.z + v.w * v.w;
    }
    s1 += __shfl_xor(s1, 1); s2 += __shfl_xor(s2, 1);
    s1 += __shfl_xor(s1, 2); s2 += __shfl_xor(s2, 2);
    s1 += __shfl_xor(s1, 4); s2 += __shfl_xor(s2, 4);
    const float mu = s1 * (1.f / 128.f);
    const float var = s2 * (1.f / 128.f) - mu * mu;
    if (q == 0) { mus[row] = mu; invs[row] = rsqrtf(var + 1e-5f); }
}

// ---------------------------------------------------------------------------
// K2: O-proj(self) + residual + LN1 -> x (fp32) & LDS y (bf16);
// then cross-attn QKV: Q = y@Wq, K/V = encb@Wk/Wv -> Qb, Kb, Vt.
// ---------------------------------------------------------------------------
__global__ __launch_bounds__(256) void fuse_oln_qkv_kernel(
    const u16* __restrict__ A, const u16* __restrict__ Wo,
    const float* __restrict__ bo,
    const float* __restrict__ g, const float* __restrict__ bb,
    float* __restrict__ X, const u16* __restrict__ Enc,
    const u16* __restrict__ Wq, const u16* __restrict__ Wk, const u16* __restrict__ Wv,
    const float* __restrict__ bq, const float* __restrict__ bk, const float* __restrict__ bv,
    u16* __restrict__ Qb, u16* __restrict__ Kb, u16* __restrict__ Vt)
{
    __shared__ float ls[32 * 132];
    __shared__ float mus[32], invs[32];
    __shared__ alignas(16) u16 ybuf[32][136];

    const int t = threadIdx.x;
    const int w = t >> 6, lane = t & 63;
    const int ql = lane & 31, hi = lane >> 5;
    const int m0 = blockIdx.x * 32;

    {
        f32x16 acc = (f32x16)0.0f;
        const size_t arow = (size_t)(m0 + ql) * 128;
        const int nh = w * 32;
        #pragma unroll
        for (int kk = 0; kk < 8; ++kk) {
            const short8 a = *(const short8*)(A + arow + kk * 16 + 8 * hi);
            const short8 b0 = *(const short8*)(Wo + (size_t)(nh + ql) * 128 + kk * 16 + 8 * hi);
            acc = __builtin_amdgcn_mfma_f32_32x32x16_bf16(a, b0, acc, 0, 0, 0);
        }
        const int n = nh + ql;
        const float bv_ = bo[n];
        #pragma unroll
        for (int r = 0; r < 16; ++r) {
            const int row = ROWMAP(r, hi);
            const int gm = m0 + row;
            float v = acc[r] + bv_;
            if (gm < BSn) v += X[(size_t)gm * 128 + n];
            ls[row * 132 + n] = v;
        }
    }
    __syncthreads();
    ln_stats(ls, mus, invs, t);
    __syncthreads();
    #pragma unroll
    for (int it = 0; it < 4; ++it) {
        const int idx = it * 256 + t;
        const int row = idx >> 5, cg = (idx & 31) * 4;
        const int gm = m0 + row;
        const float4 v = *(const float4*)&ls[row * 132 + cg];
        const float mu = mus[row], inv = invs[row];
        const float4 gv = *(const float4*)&g[cg];
        const float4 bv2 = *(const float4*)&bb[cg];
        float4 y;
        y.x = (v.x - mu) * inv * gv.x + bv2.x;
        y.y = (v.y - mu) * inv * gv.y + bv2.y;
        y.z = (v.z - mu) * inv * gv.z + bv2.z;
        y.w = (v.w - mu) * inv * gv.w + bv2.w;
        if (gm < BSn) *(float4*)&X[(size_t)gm * 128 + cg] = y;
        uint2 u;
        u.x = cvtpk_bf16(y.x, y.y);
        u.y = cvtpk_bf16(y.z, y.w);
        *(uint2*)&ybuf[row][cg] = u;
    }
    __syncthreads();

    #pragma unroll
    for (int z = 0; z < 3; ++z) {
        const u16* W = (z == 0) ? Wq : (z == 1) ? Wk : Wv;
        const float* Bi = (z == 0) ? bq : (z == 1) ? bk : bv;
        f32x16 acc = (f32x16)0.0f;
        const int nh = w * 32;
        #pragma unroll
        for (int kk = 0; kk < 8; ++kk) {
            short8 a;
            if (z == 0) a = *(const short8*)&ybuf[ql][kk * 16 + 8 * hi];
            else        a = *(const short8*)(Enc + (size_t)(m0 + ql) * 128 + kk * 16 + 8 * hi);
            const short8 b0 = *(const short8*)(W + (size_t)(nh + ql) * 128 + kk * 16 + 8 * hi);
            acc = __builtin_amdgcn_mfma_f32_32x32x16_bf16(a, b0, acc, 0, 0, 0);
        }
        const int n = nh + ql;
        const float bv_ = Bi[n];
        const int h = n >> 4, d = n & 15;
        #pragma unroll
        for (int r = 0; r < 16; ++r) {
            const int m = m0 + ROWMAP(r, hi);
            if (m >= BSn) continue;
            float v = acc[r] + bv_;
            const int bq_ = (m >= Sn) ? 1 : 0;
            const int s = m - bq_ * Sn;
            const int bh = bq_ * 8 + h;
            if (z == 0)      Qb[((size_t)bh * Sn + s) * 16 + d] = f2bf(v * QSCALE);
            else if (z == 1) Kb[((size_t)bh * Sn + s) * 16 + d] = f2bf(v);
            else             Vt[((size_t)bh * 16 + d) * VTJ + (s >> 5) * 32 + GPERM(s & 31)] = f2bf(v);
        }
    }
}

// ---------------------------------------------------------------------------
// K4: O-proj(cross) + residual + LN2 + FF1 + FF2 + residual + LN3 -> x;
// MODE=1: + next layer's self-attn QKV.  MODE=2: + output projection (last
// layer) -- out = y3 @ out_w + out_b computed from the fp32 LDS tile.
// ---------------------------------------------------------------------------
template <int MODE>
__global__ __launch_bounds__(256) void fuse_ffn_kernel(
    const u16* __restrict__ A, const u16* __restrict__ Wo,
    const float* __restrict__ bo,
    const float* __restrict__ g2, const float* __restrict__ b2ln,
    const u16* __restrict__ W1, const float* __restrict__ b1,
    const u16* __restrict__ W2, const float* __restrict__ b2f,
    const float* __restrict__ g3, const float* __restrict__ b3ln,
    float* __restrict__ X,
    const u16* __restrict__ Wq, const u16* __restrict__ Wk, const u16* __restrict__ Wv,
    const float* __restrict__ bq, const float* __restrict__ bk, const float* __restrict__ bv,
    u16* __restrict__ Qb, u16* __restrict__ Kb, u16* __restrict__ Vt,
    const float* __restrict__ out_w, const float* __restrict__ out_b,
    float* __restrict__ Out)
{
    __shared__ float ls[32 * 132];
    __shared__ float mus[32], invs[32];
    __shared__ alignas(16) u16 ybuf[32][136];
    __shared__ alignas(16) u16 hbuf[32][536];

    const int t = threadIdx.x;
    const int w = t >> 6, lane = t & 63;
    const int ql = lane & 31, hi = lane >> 5;
    const int m0 = blockIdx.x * 32;

    {
        f32x16 acc = (f32x16)0.0f;
        const size_t arow = (size_t)(m0 + ql) * 128;
        const int nh = w * 32;
        #pragma unroll
        for (int kk = 0; kk < 8; ++kk) {
            const short8 a = *(const short8*)(A + arow + kk * 16 + 8 * hi);
            const short8 b0 = *(const short8*)(Wo + (size_t)(nh + ql) * 128 + kk * 16 + 8 * hi);
            acc = __builtin_amdgcn_mfma_f32_32x32x16_bf16(a, b0, acc, 0, 0, 0);
        }
        const int n = nh + ql;
        const float bv_ = bo[n];
        #pragma unroll
        for (int r = 0; r < 16; ++r) {
            const int row = ROWMAP(r, hi);
            const int gm = m0 + row;
            float v = acc[r] + bv_;
            if (gm < BSn) v += X[(size_t)gm * 128 + n];
            ls[row * 132 + n] = v;
        }
    }
    __syncthreads();
    ln_stats(ls, mus, invs, t);
    __syncthreads();
    #pragma unroll
    for (int it = 0; it < 4; ++it) {
        const int idx = it * 256 + t;
        const int row = idx >> 5, cg = (idx & 31) * 4;
        const float4 v = *(const float4*)&ls[row * 132 + cg];
        const float mu = mus[row], inv = invs[row];
        const float4 gv = *(const float4*)&g2[cg];
        const float4 bv2 = *(const float4*)&b2ln[cg];
        float4 y;
        y.x = (v.x - mu) * inv * gv.x + bv2.x;
        y.y = (v.y - mu) * inv * gv.y + bv2.y;
        y.z = (v.z - mu) * inv * gv.z + bv2.z;
        y.w = (v.w - mu) * inv * gv.w + bv2.w;
        *(float4*)&ls[row * 132 + cg] = y;
        uint2 u;
        u.x = cvtpk_bf16(y.x, y.y);
        u.y = cvtpk_bf16(y.z, y.w);
        *(uint2*)&ybuf[row][cg] = u;
    }
    __syncthreads();

    #pragma unroll
    for (int nt = 0; nt < 4; ++nt) {
        const int n0 = w * 128 + nt * 32;
        f32x16 acc = (f32x16)0.0f;
        #pragma unroll
        for (int kk = 0; kk < 8; ++kk) {
            const short8 a = *(const short8*)&ybuf[ql][kk * 16 + 8 * hi];
            const short8 b0 = *(const short8*)(W1 + (size_t)(n0 + ql) * 128 + kk * 16 + 8 * hi);
            acc = __builtin_amdgcn_mfma_f32_32x32x16_bf16(a, b0, acc, 0, 0, 0);
        }
        const int n = n0 + ql;
        const float bv_ = b1[n];
        #pragma unroll
        for (int r = 0; r < 16; ++r) {
            const int row = ROWMAP(r, hi);
            hbuf[row][n] = f2bf(fmaxf(acc[r] + bv_, 0.f));
        }
    }
    __syncthreads();

    {
        f32x16 acc = (f32x16)0.0f;
        const int nh = w * 32;
        #pragma unroll
        for (int kk = 0; kk < 32; ++kk) {
            const short8 a = *(const short8*)&hbuf[ql][kk * 16 + 8 * hi];
            const short8 b0 = *(const short8*)(W2 + (size_t)(nh + ql) * 512 + kk * 16 + 8 * hi);
            acc = __builtin_amdgcn_mfma_f32_32x32x16_bf16(a, b0, acc, 0, 0, 0);
        }
        const int n = nh + ql;
        const float bv_ = b2f[n];
        #pragma unroll
        for (int r = 0; r < 16; ++r) {
            const int row = ROWMAP(r, hi);
            ls[row * 132 + n] = acc[r] + bv_ + ls[row * 132 + n];
        }
    }
    __syncthreads();
    ln_stats(ls, mus, invs, t);
    __syncthreads();
    #pragma unroll
    for (int it = 0; it < 4; ++it) {
        const int idx = it * 256 + t;
        const int row = idx >> 5, cg = (idx & 31) * 4;
        const int gm = m0 + row;
        const float4 v = *(const float4*)&ls[row * 132 + cg];
        const float mu = mus[row], inv = invs[row];
        const float4 gv = *(const float4*)&g3[cg];
        const float4 bv2 = *(const float4*)&b3ln[cg];
        float4 y;
        y.x = (v.x - mu) * inv * gv.x + bv2.x;
        y.y = (v.y - mu) * inv * gv.y + bv2.y;
        y.z = (v.z - mu) * inv * gv.z + bv2.z;
        y.w = (v.w - mu) * inv * gv.w + bv2.w;
        if (gm < BSn) *(float4*)&X[(size_t)gm * 128 + cg] = y;
        uint2 u;
        u.x = cvtpk_bf16(y.x, y.y);
        u.y = cvtpk_bf16(y.z, y.w);
        *(uint2*)&ybuf[row][cg] = u;
        if (MODE == 2) *(float4*)&ls[row * 132 + cg] = y;   // keep y3 fp32 for out-proj
    }

    if (MODE == 1) {
        __syncthreads();
        #pragma unroll
        for (int z = 0; z < 3; ++z) {
            const u16* W = (z == 0) ? Wq : (z == 1) ? Wk : Wv;
            const float* Bi = (z == 0) ? bq : (z == 1) ? bk : bv;
            f32x16 acc = (f32x16)0.0f;
            const int nh = w * 32;
            #pragma unroll
            for (int kk = 0; kk < 8; ++kk) {
                const short8 a = *(const short8*)&ybuf[ql][kk * 16 + 8 * hi];
                const short8 b0 = *(const short8*)(W + (size_t)(nh + ql) * 128 + kk * 16 + 8 * hi);
                acc = __builtin_amdgcn_mfma_f32_32x32x16_bf16(a, b0, acc, 0, 0, 0);
            }
            const int n = nh + ql;
            const float bv_ = Bi[n];
            const int h = n >> 4, d = n & 15;
            #pragma unroll
            for (int r = 0; r < 16; ++r) {
                const int m = m0 + ROWMAP(r, hi);
                if (m >= BSn) continue;
                float v = acc[r] + bv_;
                const int bq_ = (m >= Sn) ? 1 : 0;
                const int s = m - bq_ * Sn;
                const int bh = bq_ * 8 + h;
                if (z == 0)      Qb[((size_t)bh * Sn + s) * 16 + d] = f2bf(v * QSCALE);
                else if (z == 1) Kb[((size_t)bh * Sn + s) * 16 + d] = f2bf(v);
                else             Vt[((size_t)bh * 16 + d) * VTJ + (s >> 5) * 32 + GPERM(s & 31)] = f2bf(v);
            }
        }
    }

    if (MODE == 2) {
        __syncthreads();
        // out[gm][0..15] = y3 @ out_w + out_b   (fp32 from ls; 2 cols/thread)
        const int row = t >> 3;                 // 0..31
        const int n0 = (t & 7) * 2;             // 0,2,...,14
        const int gm = m0 + row;
        if (gm < BSn) {
            const float* lr = &ls[row * 132];
            float a0 = 0.f, a1 = 0.f;
            #pragma unroll 8
            for (int k = 0; k < 128; ++k) {
                const float xv = lr[k];
                a0 = fmaf(xv, out_w[k * 16 + n0], a0);
                a1 = fmaf(xv, out_w[k * 16 + n0 + 1], a1);
            }
            Out[(size_t)gm * 16 + n0]     = a0 + out_b[n0];
            Out[(size_t)gm * 16 + n0 + 1] = a1 + out_b[n0 + 1];
        }
    }
}

// ---------------------------------------------------------------------------
// MFMA flash attention, 8-way split-KV (512 threads), exp2-domain softmax.
// ---------------------------------------------------------------------------
template <int MASK>
__global__ __launch_bounds__(512) void flash_mfma(
    const u16* __restrict__ Qb, const u16* __restrict__ Kb,
    const u16* __restrict__ Vt, u16* __restrict__ Ob)
{
    __shared__ float mrg[8][64][10];

    const int wid = threadIdx.x >> 6;
    const int lane = threadIdx.x & 63;
    const int bh = blockIdx.y;
    const int b = bh >> 3, h = bh & 7;

    if (MASK && blockIdx.x == NQT) {
        const int d = threadIdx.x & 15, part = threadIdx.x >> 4;   // part in [0,32)
        const u16* row = Vt + ((size_t)bh * 16 + d) * VTJ;
        float s = 0.f;
        for (int j = part; j < VTJ; j += 32) s += bf2f(row[j]);
        ((float*)mrg)[part * 16 + d] = s;
        __syncthreads();
        if (threadIdx.x < 16) {
            float tot = 0.f;
            #pragma unroll
            for (int p = 0; p < 32; ++p) tot += ((float*)mrg)[p * 16 + threadIdx.x];
            Ob[((size_t)(b * Sn + (Sn - 1))) * 128 + h * 16 + threadIdx.x] =
                f2bf(tot * (1.f / (float)Sn));
        }
        return;
    }

    const int ql = lane & 31, hi = lane >> 5;
    const int qt = blockIdx.x;
    const int qrow = qt * 32 + ql;
    const int qr = (qrow < Sn) ? qrow : (Sn - 1);
    const short8 qf = *(const short8*)(Qb + ((size_t)bh * Sn + qr) * 16 + 8 * hi);
    const u16* kbase = Kb + (size_t)bh * Sn * 16;
    const u16* vbase = Vt + ((size_t)bh * 16 + (ql & 15)) * VTJ;

    f32x16 acc = (f32x16)0.0f;
    float m = -INFINITY, lsum = 0.f;

    int jt = (MASK ? qt : 0) + wid;
    short8 kf = (short8)0, va = (short8)0, vb2 = (short8)0;
    if (jt < NQT) {
        int krow = jt * 32 + ql; if (krow >= Sn) krow = Sn - 1;
        kf  = *(const short8*)(kbase + (size_t)krow * 16 + 8 * hi);
        va  = *(const short8*)(vbase + jt * 32 + 8 * hi);
        vb2 = *(const short8*)(vbase + jt * 32 + 16 + 8 * hi);
    }

    for (; jt < NQT; jt += 8) {
        short8 kn = kf, van = va, vbn = vb2;
        if (jt + 8 < NQT) {
            int nrow = (jt + 8) * 32 + ql; if (nrow >= Sn) nrow = Sn - 1;
            kn  = *(const short8*)(kbase + (size_t)nrow * 16 + 8 * hi);
            van = *(const short8*)(vbase + (jt + 8) * 32 + 8 * hi);
            vbn = *(const short8*)(vbase + (jt + 8) * 32 + 16 + 8 * hi);
        }

        const f32x16 sc = __builtin_amdgcn_mfma_f32_32x32x16_bf16(kf, qf, (f32x16)0.0f, 0, 0, 0);

        float sv[16];
        #pragma unroll
        for (int r = 0; r < 16; ++r) sv[r] = sc[r];

        if (MASK && jt == qt) {     // only wave 0 ever hits jt == qt
            #pragma unroll
            for (int r = 0; r < 16; ++r)
                if (!(ROWMAP(r, hi) > ql)) sv[r] = -1e9f;
        }
        if (jt == NQT - 1) {
            #pragma unroll
            for (int r = 0; r < 16; ++r)
                if (1792 + ROWMAP(r, hi) >= Sn) sv[r] = -1e30f;
        }

        // depth-3 max tree (v_max3 fusible)
        const float a0 = fmaxf(fmaxf(sv[0], sv[1]), sv[2]);
        const float a1 = fmaxf(fmaxf(sv[3], sv[4]), sv[5]);
        const float a2 = fmaxf(fmaxf(sv[6], sv[7]), sv[8]);
        const float a3 = fmaxf(fmaxf(sv[9], sv[10]), sv[11]);
        const float a4 = fmaxf(fmaxf(sv[12], sv[13]), sv[14]);
        const float b0m = fmaxf(fmaxf(a0, a1), a2);
        const float b1m = fmaxf(fmaxf(a3, a4), sv[15]);
        const float tmax = xhalf_max(fmaxf(b0m, b1m));

        // unconditional online-softmax rescale
        const float mnew = fmaxf(m, tmax);
        const float corr = EXP2(m - mnew);
        m = mnew;
        lsum *= corr;
        #pragma unroll
        for (int r = 0; r < 16; ++r) acc[r] *= corr;

        float p[16];
        float ps = 0.f;
        #pragma unroll
        for (int r = 0; r < 16; ++r) { p[r] = EXP2(sv[r] - m); ps += p[r]; }
        lsum += ps;

        union { u32 u[4]; short8 s; } B0c, B1c;
        B0c.u[0] = cvtpk_bf16(p[0],  p[1]);  B0c.u[1] = cvtpk_bf16(p[2],  p[3]);
        B0c.u[2] = cvtpk_bf16(p[4],  p[5]);  B0c.u[3] = cvtpk_bf16(p[6],  p[7]);
        B1c.u[0] = cvtpk_bf16(p[8],  p[9]);  B1c.u[1] = cvtpk_bf16(p[10], p[11]);
        B1c.u[2] = cvtpk_bf16(p[12], p[13]); B1c.u[3] = cvtpk_bf16(p[14], p[15]);

        acc = __builtin_amdgcn_mfma_f32_32x32x16_bf16(va,  B0c.s, acc, 0, 0, 0);
        acc = __builtin_amdgcn_mfma_f32_32x32x16_bf16(vb2, B1c.s, acc, 0, 0, 0);

        kf = kn; va = van; vb2 = vbn;
    }

    mrg[wid][lane][0] = m;
    mrg[wid][lane][1] = lsum;
    #pragma unroll
    for (int r = 0; r < 8; ++r) mrg[wid][lane][2 + r] = acc[r];
    __syncthreads();

    if (wid == 0) {
        float mstar = mrg[0][lane][0];
        #pragma unroll
        for (int w2 = 1; w2 < 8; ++w2) mstar = fmaxf(mstar, mrg[w2][lane][0]);
        float lt = 0.f;
        float accf[8] = {};
        #pragma unroll
        for (int w2 = 0; w2 < 8; ++w2) {
            const float sc2 = EXP2(mrg[w2][lane][0] - mstar);
            lt += mrg[w2][lane][1] * sc2;
            #pragma unroll
            for (int r = 0; r < 8; ++r) accf[r] = fmaf(mrg[w2][lane][2 + r], sc2, accf[r]);
        }
        const float ltot = xhalf_sum(lt);
        const float inv = 1.f / ltot;
        if (qrow < Sn && !(MASK && qrow == Sn - 1)) {
            u16* op = Ob + ((size_t)(b * Sn + qrow)) * 128 + h * 16;
            uint2 u0, u1;
            u0.x = cvtpk_bf16(accf[0] * inv, accf[1] * inv);
            u0.y = cvtpk_bf16(accf[2] * inv, accf[3] * inv);
            u1.x = cvtpk_bf16(accf[4] * inv, accf[5] * inv);
            u1.y = cvtpk_bf16(accf[6] * inv, accf[7] * inv);
            *(uint2*)(op + 4 * hi) = u0;
            *(uint2*)(op + 8 + 4 * hi) = u1;
        }
    }
}

// ---------------------------------------------------------------------------
extern "C" void kernel_launch(void* const* d_in, const int* in_sizes, int n_in,
                              void* d_out, int out_size, void* d_ws, size_t ws_size,
                              hipStream_t stream)
{
    const float* latent = (const float*)d_in[0];
    const float* lp_w1  = (const float*)d_in[1];
    const float* lp_b1  = (const float*)d_in[2];
    const float* lp_w2  = (const float*)d_in[3];
    const float* lp_b2  = (const float*)d_in[4];
    const float* out_w  = (const float*)d_in[5];
    const float* out_b  = (const float*)d_in[6];
    const float* sa_wq = (const float*)d_in[7];  const float* sa_bq = (const float*)d_in[8];
    const float* sa_wk = (const float*)d_in[9];  const float* sa_bk = (const float*)d_in[10];
    const float* sa_wv = (const float*)d_in[11]; const float* sa_bv = (const float*)d_in[12];
    const float* sa_wo = (const float*)d_in[13]; const float* sa_bo = (const float*)d_in[14];
    const float* ca_wq = (const float*)d_in[15]; const float* ca_bq = (const float*)d_in[16];
    const float* ca_wk = (const float*)d_in[17]; const float* ca_bk = (const float*)d_in[18];
    const float* ca_wv = (const float*)d_in[19]; const float* ca_bv = (const float*)d_in[20];
    const float* ca_wo = (const float*)d_in[21]; const float* ca_bo = (const float*)d_in[22];
    const float* ff_w1 = (const float*)d_in[23]; const float* ff_b1 = (const float*)d_in[24];
    const float* ff_w2 = (const float*)d_in[25]; const float* ff_b2 = (const float*)d_in[26];
    const float* ln1g = (const float*)d_in[27]; const float* ln1b = (const float*)d_in[28];
    const float* ln2g = (const float*)d_in[29]; const float* ln2b = (const float*)d_in[30];
    const float* ln3g = (const float*)d_in[31]; const float* ln3b = (const float*)d_in[32];

    float* ws = (float*)d_ws;
    float* x    = ws;                         // 460800 f
    float* hlat = ws + 460800;                // 512 f
    u16* xb   = (u16*)(ws + 461312);          // MPAD*128 us = 237568 f (layer-0 only)
    u16* encb = (u16*)(ws + 698880);          // 237568 f
    u16* ob   = (u16*)(ws + 936448);          // 237568 f
    u16* Qb   = (u16*)(ws + 2124288);         // 230400 f   (slack layout: load-bearing)
    u16* Kb   = (u16*)(ws + 2354688);         // 230400 f
    u16* Vt   = (u16*)(ws + 2585088);         // 16*16*1824 us = 233472 f
    u16* wt_saq = (u16*)(ws + 2818560);       // 8 square mats, 49152 f each
    u16* wt_sak = wt_saq + 6 * 16384;
    u16* wt_sav = wt_sak + 6 * 16384;
    u16* wt_sao = wt_sav + 6 * 16384;
    u16* wt_caq = wt_sao + 6 * 16384;
    u16* wt_cak = wt_caq + 6 * 16384;
    u16* wt_cav = wt_cak + 6 * 16384;
    u16* wt_cao = wt_cav + 6 * 16384;
    u16* wt1  = (u16*)(ws + 3211776);         // [6][512][128] us = 196608 f
    u16* wt2  = (u16*)(ws + 3408384);         // [6][128][512] us = 196608 f

    wprep_kernel<<<dim3(6176), dim3(256), 0, stream>>>(
        sa_wq, sa_wk, sa_wv, sa_wo, ca_wq, ca_wk, ca_wv, ca_wo,
        wt_saq, wt_sak, wt_sav, wt_sao, wt_caq, wt_cak, wt_cav, wt_cao,
        ff_w1, wt1, ff_w2, wt2, Vt);

    lat_h_kernel<<<dim3(2), dim3(256), 0, stream>>>(latent, lp_w1, lp_b1, hlat);
    dec_kernel<<<dim3(900), dim3(256), 0, stream>>>(hlat, lp_w2, lp_b2, x, xb, encb);

    const dim3 thr(256), thrF(512);
    const dim3 gFm(NQT + 1, 16), gFc(NQT, 16), gFuse(113);

    // layer-0 self-attn QKV from xb
    mm_qkv_kernel<<<dim3(57, 1, 3), thr, 0, stream>>>(
        xb, xb, wt_saq, wt_sak, wt_sav, sa_bq, sa_bk, sa_bv, Qb, Kb, Vt);

    for (int i = 0; i < Ln; ++i) {
        const size_t wOff = (size_t)i * 16384;
        const size_t bOff = (size_t)i * 128;
        const size_t fOff = (size_t)i * 65536;
        const size_t f1b  = (size_t)i * 512;
        const size_t wNxt = (size_t)(i + 1) * 16384;
        const size_t bNxt = (size_t)(i + 1) * 128;

        flash_mfma<1><<<gFm, thrF, 0, stream>>>(Qb, Kb, Vt, ob);

        fuse_oln_qkv_kernel<<<gFuse, thr, 0, stream>>>(
            ob, wt_sao + wOff, sa_bo + bOff, ln1g + bOff, ln1b + bOff, x, encb,
            wt_caq + wOff, wt_cak + wOff, wt_cav + wOff,
            ca_bq + bOff, ca_bk + bOff, ca_bv + bOff, Qb, Kb, Vt);

        flash_mfma<0><<<gFc, thrF, 0, stream>>>(Qb, Kb, Vt, ob);

        if (i < Ln - 1) {
            fuse_ffn_kernel<1><<<gFuse, thr, 0, stream>>>(
                ob, wt_cao + wOff, ca_bo + bOff, ln2g + bOff, ln2b + bOff,
                wt1 + fOff, ff_b1 + f1b, wt2 + fOff, ff_b2 + bOff,
                ln3g + bOff, ln3b + bOff, x,
                wt_saq + wNxt, wt_sak + wNxt, wt_sav + wNxt,
                sa_bq + bNxt, sa_bk + bNxt, sa_bv + bNxt, Qb, Kb, Vt,
                out_w, out_b, (float*)d_out);
        } else {
            fuse_ffn_kernel<2><<<gFuse, thr, 0, stream>>>(
                ob, wt_cao + wOff, ca_bo + bOff, ln2g + bOff, ln2b + bOff,
                wt1 + fOff, ff_b1 + f1b, wt2 + fOff, ff_b2 + bOff,
                ln3g + bOff, ln3b + bOff, x,
                wt_saq, wt_sak, wt_sav, sa_bq, sa_bk, sa_bv, Qb, Kb, Vt,
                out_w, out_b, (float*)d_out);
        }
    }
}